// Round 1
// baseline (964.605 us; speedup 1.0000x reference)
//
#include <hip/hip_runtime.h>
#include <math.h>

#define N_NODES 100000
#define N_EDGES 1600000
#define F_IN    128
#define F_HID   64
#define F_OUT   40

// ---------------- degree / dinv ----------------
__global__ void degree_kernel(const int* __restrict__ dst, float* __restrict__ deg, int E) {
    int i = blockIdx.x * blockDim.x + threadIdx.x;
    if (i < E) atomicAdd(&deg[dst[i]], 1.0f);
}

__global__ void dinv_kernel(const float* __restrict__ deg, float* __restrict__ dinv, int n) {
    int i = blockIdx.x * blockDim.x + threadIdx.x;
    if (i < n) dinv[i] = rsqrtf(deg[i] + 1.0f);  // +1 for self-loop
}

// ---------------- GEMM1: h1[N,64] = x[N,128] @ W1[128,64] ----------------
__global__ void gemm1_kernel(const float* __restrict__ x, const float* __restrict__ W,
                             float* __restrict__ h, int n) {
    __shared__ float Wl[F_IN * F_HID];   // 32 KB
    __shared__ float Xl[4 * F_IN];       // 4 node rows
    int tid = threadIdx.x;
    for (int i = tid; i < F_IN * F_HID; i += 256) Wl[i] = W[i];
    int node0 = blockIdx.x * 4;
    for (int i = tid; i < 4 * F_IN; i += 256) {
        int node = node0 + (i >> 7);
        Xl[i] = (node < n) ? x[(size_t)node * F_IN + (i & (F_IN - 1))] : 0.0f;
    }
    __syncthreads();
    int r    = tid >> 6;    // 0..3 -> node within block
    int col  = tid & 63;    // output feature
    int node = node0 + r;
    if (node >= n) return;
    float acc = 0.0f;
    #pragma unroll 8
    for (int k = 0; k < F_IN; ++k)
        acc += Xl[r * F_IN + k] * Wl[k * F_HID + col];
    h[(size_t)node * F_HID + col] = acc;
}

// ---------------- edge scatter, layer 1 (64 feats, one 64-lane group per edge) ----
__global__ void scatter1_kernel(const int* __restrict__ src, const int* __restrict__ dst,
                                const float* __restrict__ dinv, const float* __restrict__ h,
                                float* __restrict__ agg, int E) {
    int e    = blockIdx.x * 4 + (threadIdx.x >> 6);
    int lane = threadIdx.x & 63;
    if (e >= E) return;
    int s = src[e], d = dst[e];
    float w = dinv[s] * dinv[d];
    atomicAdd(&agg[(size_t)d * F_HID + lane], h[(size_t)s * F_HID + lane] * w);
}

// ---------------- combine + relu: agg1 = relu(agg1 + h1/deg + b1) ----------------
__global__ void combine1_kernel(float* __restrict__ agg, const float* __restrict__ h,
                                const float* __restrict__ dinv, const float* __restrict__ b,
                                int n) {
    int i = blockIdx.x * blockDim.x + threadIdx.x;
    if (i >= n * F_HID) return;
    int node = i >> 6, col = i & 63;
    float di = dinv[node];
    float v  = agg[i] + h[i] * di * di + b[col];
    agg[i] = fmaxf(v, 0.0f);
}

// ---------------- GEMM2: h2[N,40] = out1[N,64] @ W2[64,40] ----------------
__global__ void gemm2_kernel(const float* __restrict__ a, const float* __restrict__ W,
                             float* __restrict__ h, int n) {
    __shared__ float Wl[F_HID * F_OUT];  // 10 KB
    int tid = threadIdx.x;
    for (int i = tid; i < F_HID * F_OUT; i += 256) Wl[i] = W[i];
    __syncthreads();
    long long idx = (long long)blockIdx.x * 256 + tid;
    if (idx >= (long long)n * F_OUT) return;
    int node = (int)(idx / F_OUT);
    int col  = (int)(idx - (long long)node * F_OUT);
    const float* arow = a + (size_t)node * F_HID;
    float acc = 0.0f;
    #pragma unroll 8
    for (int k = 0; k < F_HID; ++k)
        acc += arow[k] * Wl[k * F_OUT + col];
    h[idx] = acc;
}

// ---------------- edge scatter, layer 2 (40 feats) ----------------
__global__ void scatter2_kernel(const int* __restrict__ src, const int* __restrict__ dst,
                                const float* __restrict__ dinv, const float* __restrict__ h,
                                float* __restrict__ agg, int E) {
    int e    = blockIdx.x * 4 + (threadIdx.x >> 6);
    int lane = threadIdx.x & 63;
    if (e >= E || lane >= F_OUT) return;
    int s = src[e], d = dst[e];
    float w = dinv[s] * dinv[d];
    atomicAdd(&agg[(size_t)d * F_OUT + lane], h[(size_t)s * F_OUT + lane] * w);
}

// ---------------- final: out = log_softmax(agg2 + h2/deg + b2, axis=1) ----------
__global__ void final_kernel(const float* __restrict__ agg, const float* __restrict__ h,
                             const float* __restrict__ dinv, const float* __restrict__ b,
                             float* __restrict__ out, int n) {
    int node = blockIdx.x * 4 + (threadIdx.x >> 6);
    int lane = threadIdx.x & 63;
    if (node >= n) return;
    float val = 0.0f, v = -INFINITY;
    if (lane < F_OUT) {
        float di = dinv[node];
        size_t i = (size_t)node * F_OUT + lane;
        val = agg[i] + h[i] * di * di + b[lane];
        v = val;
    }
    #pragma unroll
    for (int off = 32; off; off >>= 1) v = fmaxf(v, __shfl_xor(v, off));
    float p = (lane < F_OUT) ? __expf(val - v) : 0.0f;
    #pragma unroll
    for (int off = 32; off; off >>= 1) p += __shfl_xor(p, off);
    float lse = v + __logf(p);
    if (lane < F_OUT) out[(size_t)node * F_OUT + lane] = val - lse;
}

extern "C" void kernel_launch(void* const* d_in, const int* in_sizes, int n_in,
                              void* d_out, int out_size, void* d_ws, size_t ws_size,
                              hipStream_t stream) {
    const float* x  = (const float*)d_in[0];
    const int*   ei = (const int*)d_in[1];      // [2,E] int32: row0=src, row1=dst
    const float* W1 = (const float*)d_in[2];
    const float* b1 = (const float*)d_in[3];
    const float* W2 = (const float*)d_in[4];
    const float* b2 = (const float*)d_in[5];
    const int* src = ei;
    const int* dst = ei + N_EDGES;

    // workspace layout (floats): [deg N | agg1 N*64 | agg2 N*40 | dinv N | h1 N*64 | h2 N*40]
    float* ws   = (float*)d_ws;
    float* deg  = ws;
    float* agg1 = deg  + N_NODES;
    float* agg2 = agg1 + (size_t)N_NODES * F_HID;
    float* dinv = agg2 + (size_t)N_NODES * F_OUT;
    float* h1   = dinv + N_NODES;
    float* h2   = h1   + (size_t)N_NODES * F_HID;
    float* out  = (float*)d_out;

    // zero deg+agg1+agg2 (contiguous)
    hipMemsetAsync(deg, 0, (size_t)N_NODES * (1 + F_HID + F_OUT) * sizeof(float), stream);

    degree_kernel<<<(N_EDGES + 255) / 256, 256, 0, stream>>>(dst, deg, N_EDGES);
    dinv_kernel<<<(N_NODES + 255) / 256, 256, 0, stream>>>(deg, dinv, N_NODES);
    gemm1_kernel<<<(N_NODES + 3) / 4, 256, 0, stream>>>(x, W1, h1, N_NODES);
    scatter1_kernel<<<(N_EDGES + 3) / 4, 256, 0, stream>>>(src, dst, dinv, h1, agg1, N_EDGES);
    combine1_kernel<<<(N_NODES * F_HID + 255) / 256, 256, 0, stream>>>(agg1, h1, dinv, b1, N_NODES);
    gemm2_kernel<<<((N_NODES * F_OUT) + 255) / 256, 256, 0, stream>>>(agg1, W2, h2, N_NODES);
    scatter2_kernel<<<(N_EDGES + 3) / 4, 256, 0, stream>>>(src, dst, dinv, h2, agg2, N_EDGES);
    final_kernel<<<(N_NODES + 3) / 4, 256, 0, stream>>>(agg2, h2, dinv, b2, out, N_NODES);
}

// Round 2
// 656.215 us; speedup vs baseline: 1.4700x; 1.4700x over previous
//
#include <hip/hip_runtime.h>
#include <math.h>

#define N_NODES 100000
#define N_EDGES 1600000
#define F_IN    128
#define F_HID   64
#define F_OUT   40
#define SCAN_B  391   // ceil(100000/256)

// ---------------- histogram of dst (in-degree) ----------------
__global__ void hist_kernel(const int* __restrict__ dst, int* __restrict__ hist, int E) {
    int i = blockIdx.x * blockDim.x + threadIdx.x;
    if (i < E) atomicAdd(&hist[dst[i]], 1);
}

// ---------------- 3-phase exclusive scan over hist ----------------
__global__ void scan1_kernel(const int* __restrict__ hist, int* __restrict__ local,
                             int* __restrict__ blocksum, int n) {
    __shared__ int tmp[256];
    int i = blockIdx.x * 256 + threadIdx.x;
    int v = (i < n) ? hist[i] : 0;
    tmp[threadIdx.x] = v;
    __syncthreads();
    for (int off = 1; off < 256; off <<= 1) {
        int t = (threadIdx.x >= off) ? tmp[threadIdx.x - off] : 0;
        __syncthreads();
        tmp[threadIdx.x] += t;
        __syncthreads();
    }
    if (i < n) local[i] = tmp[threadIdx.x] - v;          // exclusive
    if (threadIdx.x == 255) blocksum[blockIdx.x] = tmp[255];
}

__global__ void scan2_kernel(int* __restrict__ blocksum, int nb) {
    __shared__ int tmp[512];
    int v = (threadIdx.x < nb) ? blocksum[threadIdx.x] : 0;
    tmp[threadIdx.x] = v;
    __syncthreads();
    for (int off = 1; off < 512; off <<= 1) {
        int t = (threadIdx.x >= off) ? tmp[threadIdx.x - off] : 0;
        __syncthreads();
        tmp[threadIdx.x] += t;
        __syncthreads();
    }
    if (threadIdx.x < nb) blocksum[threadIdx.x] = tmp[threadIdx.x] - v;  // exclusive
}

__global__ void scan3_kernel(const int* __restrict__ hist, const int* __restrict__ local,
                             const int* __restrict__ blocksum, int* __restrict__ rowstart,
                             int* __restrict__ cursor, float* __restrict__ dinv, int n, int E) {
    int i = blockIdx.x * 256 + threadIdx.x;
    if (i >= n) return;
    int r = local[i] + blocksum[blockIdx.x];
    rowstart[i] = r;
    cursor[i]   = r;
    dinv[i]     = rsqrtf((float)hist[i] + 1.0f);   // +1 self-loop
    if (i == 0) rowstart[n] = E;
}

// ---------------- CSR fill (counting-sort scatter of src ids) ----------------
__global__ void fill_kernel(const int* __restrict__ src, const int* __restrict__ dst,
                            int* __restrict__ cursor, int* __restrict__ csr_src, int E) {
    int e = blockIdx.x * blockDim.x + threadIdx.x;
    if (e >= E) return;
    int d = dst[e];
    int pos = atomicAdd(&cursor[d], 1);
    csr_src[pos] = src[e];
}

// ---------------- GEMM1: h1[N,64] = x[N,128] @ W1[128,64] ----------------
__global__ void gemm1_kernel(const float* __restrict__ x, const float* __restrict__ W,
                             float* __restrict__ h, int n) {
    __shared__ float Wl[F_IN * F_HID];   // 32 KB
    __shared__ float Xl[4 * F_IN];
    int tid = threadIdx.x;
    for (int i = tid; i < F_IN * F_HID; i += 256) Wl[i] = W[i];
    int node0 = blockIdx.x * 4;
    for (int i = tid; i < 4 * F_IN; i += 256) {
        int node = node0 + (i >> 7);
        Xl[i] = (node < n) ? x[(size_t)node * F_IN + (i & (F_IN - 1))] : 0.0f;
    }
    __syncthreads();
    int r    = tid >> 6;
    int col  = tid & 63;
    int node = node0 + r;
    if (node >= n) return;
    float acc = 0.0f;
    #pragma unroll 8
    for (int k = 0; k < F_IN; ++k)
        acc += Xl[r * F_IN + k] * Wl[k * F_HID + col];
    h[(size_t)node * F_HID + col] = acc;
}

// ---------------- layer-1 gather + combine + ReLU (wave per node) ----------------
__global__ void agg1_kernel(const int* __restrict__ rowstart, const int* __restrict__ csr,
                            const float* __restrict__ dinv, const float* __restrict__ h,
                            const float* __restrict__ b, float* __restrict__ out, int n) {
    int node = blockIdx.x * 4 + (threadIdx.x >> 6);
    int lane = threadIdx.x & 63;
    if (node >= n) return;
    int beg = rowstart[node], end = rowstart[node + 1];
    float acc = 0.0f;
    for (int j0 = beg; j0 < end; j0 += 64) {
        int idx = j0 + lane;
        int sid = (idx < end) ? csr[idx] : 0;
        float dv = (idx < end) ? dinv[sid] : 0.0f;
        int nIn = min(64, end - j0);
        for (int j = 0; j < nIn; ++j) {
            int   s = __shfl(sid, j);
            float w = __shfl(dv, j);
            acc += h[(size_t)s * F_HID + lane] * w;
        }
    }
    float di = dinv[node];
    float v = acc * di + h[(size_t)node * F_HID + lane] * di * di + b[lane];
    out[(size_t)node * F_HID + lane] = fmaxf(v, 0.0f);
}

// ---------------- GEMM2: h2[N,40] = out1[N,64] @ W2[64,40] ----------------
__global__ void gemm2_kernel(const float* __restrict__ a, const float* __restrict__ W,
                             float* __restrict__ h, int n) {
    __shared__ float Wl[F_HID * F_OUT];
    int tid = threadIdx.x;
    for (int i = tid; i < F_HID * F_OUT; i += 256) Wl[i] = W[i];
    __syncthreads();
    long long idx = (long long)blockIdx.x * 256 + tid;
    if (idx >= (long long)n * F_OUT) return;
    int node = (int)(idx / F_OUT);
    int col  = (int)(idx - (long long)node * F_OUT);
    const float* arow = a + (size_t)node * F_HID;
    float acc = 0.0f;
    #pragma unroll 8
    for (int k = 0; k < F_HID; ++k)
        acc += arow[k] * Wl[k * F_OUT + col];
    h[idx] = acc;
}

// ---------------- layer-2 gather + combine + log_softmax (wave per node) --------
__global__ void agg2_kernel(const int* __restrict__ rowstart, const int* __restrict__ csr,
                            const float* __restrict__ dinv, const float* __restrict__ h,
                            const float* __restrict__ b, float* __restrict__ out, int n) {
    int node = blockIdx.x * 4 + (threadIdx.x >> 6);
    int lane = threadIdx.x & 63;
    if (node >= n) return;
    int beg = rowstart[node], end = rowstart[node + 1];
    float acc = 0.0f;
    for (int j0 = beg; j0 < end; j0 += 64) {
        int idx = j0 + lane;
        int sid = (idx < end) ? csr[idx] : 0;
        float dv = (idx < end) ? dinv[sid] : 0.0f;
        int nIn = min(64, end - j0);
        for (int j = 0; j < nIn; ++j) {
            int   s = __shfl(sid, j);
            float w = __shfl(dv, j);
            if (lane < F_OUT) acc += h[(size_t)s * F_OUT + lane] * w;
        }
    }
    float di = dinv[node];
    float val = 0.0f, m = -INFINITY;
    if (lane < F_OUT) {
        val = acc * di + h[(size_t)node * F_OUT + lane] * di * di + b[lane];
        m = val;
    }
    #pragma unroll
    for (int off = 32; off; off >>= 1) m = fmaxf(m, __shfl_xor(m, off));
    float p = (lane < F_OUT) ? __expf(val - m) : 0.0f;
    #pragma unroll
    for (int off = 32; off; off >>= 1) p += __shfl_xor(p, off);
    float lse = m + __logf(p);
    if (lane < F_OUT) out[(size_t)node * F_OUT + lane] = val - lse;
}

extern "C" void kernel_launch(void* const* d_in, const int* in_sizes, int n_in,
                              void* d_out, int out_size, void* d_ws, size_t ws_size,
                              hipStream_t stream) {
    const float* x  = (const float*)d_in[0];
    const int*   ei = (const int*)d_in[1];
    const float* W1 = (const float*)d_in[2];
    const float* b1 = (const float*)d_in[3];
    const float* W2 = (const float*)d_in[4];
    const float* b2 = (const float*)d_in[5];
    const int* src = ei;
    const int* dst = ei + N_EDGES;

    // workspace layout
    char* p = (char*)d_ws;
    int*   hist     = (int*)p;                 p += (size_t)N_NODES * 4;
    int*   local    = (int*)p;                 p += (size_t)N_NODES * 4;
    int*   blocksum = (int*)p;                 p += 512 * 4;
    int*   rowstart = (int*)p;                 p += (size_t)(N_NODES + 1) * 4;
    int*   cursor   = (int*)p;                 p += (size_t)N_NODES * 4;
    int*   csr_src  = (int*)p;                 p += (size_t)N_EDGES * 4;
    float* dinv     = (float*)p;               p += (size_t)N_NODES * 4;
    float* h1       = (float*)p;               p += (size_t)N_NODES * F_HID * 4;
    float* out1     = (float*)p;               p += (size_t)N_NODES * F_HID * 4;
    float* h2       = (float*)p;               p += (size_t)N_NODES * F_OUT * 4;
    float* out      = (float*)d_out;

    hipMemsetAsync(hist, 0, (size_t)N_NODES * 4, stream);

    hist_kernel <<<(N_EDGES + 255) / 256, 256, 0, stream>>>(dst, hist, N_EDGES);
    scan1_kernel<<<SCAN_B, 256, 0, stream>>>(hist, local, blocksum, N_NODES);
    scan2_kernel<<<1, 512, 0, stream>>>(blocksum, SCAN_B);
    scan3_kernel<<<SCAN_B, 256, 0, stream>>>(hist, local, blocksum, rowstart, cursor,
                                             dinv, N_NODES, N_EDGES);
    fill_kernel <<<(N_EDGES + 255) / 256, 256, 0, stream>>>(src, dst, cursor, csr_src, N_EDGES);
    gemm1_kernel<<<(N_NODES + 3) / 4, 256, 0, stream>>>(x, W1, h1, N_NODES);
    agg1_kernel <<<(N_NODES + 3) / 4, 256, 0, stream>>>(rowstart, csr_src, dinv, h1, b1,
                                                        out1, N_NODES);
    gemm2_kernel<<<((N_NODES * F_OUT) + 255) / 256, 256, 0, stream>>>(out1, W2, h2, N_NODES);
    agg2_kernel <<<(N_NODES + 3) / 4, 256, 0, stream>>>(rowstart, csr_src, dinv, h2, b2,
                                                        out, N_NODES);
}

// Round 3
// 530.318 us; speedup vs baseline: 1.8189x; 1.2374x over previous
//
#include <hip/hip_runtime.h>
#include <math.h>

#define N_NODES 100000
#define N_EDGES 1600000
#define F_IN    128
#define F_HID   64
#define F_OUT   40
#define SCAN_B  391   // ceil(100000/256)

__device__ __forceinline__ float4 shfl_xor_f4(float4 v, int m) {
    v.x = __shfl_xor(v.x, m); v.y = __shfl_xor(v.y, m);
    v.z = __shfl_xor(v.z, m); v.w = __shfl_xor(v.w, m);
    return v;
}

// ---------------- histogram of dst (in-degree) ----------------
__global__ void hist_kernel(const int* __restrict__ dst, int* __restrict__ hist, int E) {
    int i = blockIdx.x * blockDim.x + threadIdx.x;
    if (i < E) atomicAdd(&hist[dst[i]], 1);
}

// ---------------- 3-phase exclusive scan over hist ----------------
__global__ void scan1_kernel(const int* __restrict__ hist, int* __restrict__ local,
                             int* __restrict__ blocksum, int n) {
    __shared__ int tmp[256];
    int i = blockIdx.x * 256 + threadIdx.x;
    int v = (i < n) ? hist[i] : 0;
    tmp[threadIdx.x] = v;
    __syncthreads();
    for (int off = 1; off < 256; off <<= 1) {
        int t = (threadIdx.x >= off) ? tmp[threadIdx.x - off] : 0;
        __syncthreads();
        tmp[threadIdx.x] += t;
        __syncthreads();
    }
    if (i < n) local[i] = tmp[threadIdx.x] - v;          // exclusive
    if (threadIdx.x == 255) blocksum[blockIdx.x] = tmp[255];
}

__global__ void scan2_kernel(int* __restrict__ blocksum, int nb) {
    __shared__ int tmp[512];
    int v = (threadIdx.x < nb) ? blocksum[threadIdx.x] : 0;
    tmp[threadIdx.x] = v;
    __syncthreads();
    for (int off = 1; off < 512; off <<= 1) {
        int t = (threadIdx.x >= off) ? tmp[threadIdx.x - off] : 0;
        __syncthreads();
        tmp[threadIdx.x] += t;
        __syncthreads();
    }
    if (threadIdx.x < nb) blocksum[threadIdx.x] = tmp[threadIdx.x] - v;  // exclusive
}

__global__ void scan3_kernel(const int* __restrict__ hist, const int* __restrict__ local,
                             const int* __restrict__ blocksum, int* __restrict__ rowstart,
                             int* __restrict__ cursor, float* __restrict__ dinv, int n, int E) {
    int i = blockIdx.x * 256 + threadIdx.x;
    if (i >= n) return;
    int r = local[i] + blocksum[blockIdx.x];
    rowstart[i] = r;
    cursor[i]   = r;
    dinv[i]     = rsqrtf((float)hist[i] + 1.0f);   // +1 self-loop
    if (i == 0) rowstart[n] = E;
}

// ---------------- CSR fill (counting-sort scatter of src ids) ----------------
__global__ void fill_kernel(const int* __restrict__ src, const int* __restrict__ dst,
                            int* __restrict__ cursor, int* __restrict__ csr_src, int E) {
    int e = blockIdx.x * blockDim.x + threadIdx.x;
    if (e >= E) return;
    int d = dst[e];
    int pos = atomicAdd(&cursor[d], 1);
    csr_src[pos] = src[e];
}

// ---------------- GEMM1: h1[N,64] = x[N,128] @ W1[128,64] ----------------
// 16 nodes/block, 4 nodes per wave, k-blocked by 4 (register tiling)
__global__ void gemm1_kernel(const float* __restrict__ x, const float* __restrict__ W,
                             float* __restrict__ h, int n) {
    __shared__ float Wl[F_IN * F_HID];   // 32 KB
    __shared__ float Xl[16 * F_IN];      // 8 KB
    int tid = threadIdx.x;
    for (int i = tid; i < F_IN * F_HID; i += 256) Wl[i] = W[i];
    int node0 = blockIdx.x * 16;
    for (int i = tid; i < 16 * F_IN; i += 256) {
        int nd = node0 + (i >> 7);
        Xl[i] = (nd < n) ? x[(size_t)nd * F_IN + (i & (F_IN - 1))] : 0.0f;
    }
    __syncthreads();
    int w   = tid >> 6;     // wave 0..3 -> nodes w*4 .. w*4+3
    int col = tid & 63;
    int r0  = w * 4;
    float acc0 = 0.f, acc1 = 0.f, acc2 = 0.f, acc3 = 0.f;
    #pragma unroll 4
    for (int k0 = 0; k0 < F_IN; k0 += 4) {
        float4 xv0 = *(const float4*)&Xl[(r0 + 0) * F_IN + k0];
        float4 xv1 = *(const float4*)&Xl[(r0 + 1) * F_IN + k0];
        float4 xv2 = *(const float4*)&Xl[(r0 + 2) * F_IN + k0];
        float4 xv3 = *(const float4*)&Xl[(r0 + 3) * F_IN + k0];
        float w0 = Wl[(k0 + 0) * F_HID + col];
        float w1 = Wl[(k0 + 1) * F_HID + col];
        float w2 = Wl[(k0 + 2) * F_HID + col];
        float w3 = Wl[(k0 + 3) * F_HID + col];
        acc0 += xv0.x * w0 + xv0.y * w1 + xv0.z * w2 + xv0.w * w3;
        acc1 += xv1.x * w0 + xv1.y * w1 + xv1.z * w2 + xv1.w * w3;
        acc2 += xv2.x * w0 + xv2.y * w1 + xv2.z * w2 + xv2.w * w3;
        acc3 += xv3.x * w0 + xv3.y * w1 + xv3.z * w2 + xv3.w * w3;
    }
    int nd = node0 + r0;
    if (nd + 0 < n) h[(size_t)(nd + 0) * F_HID + col] = acc0;
    if (nd + 1 < n) h[(size_t)(nd + 1) * F_HID + col] = acc1;
    if (nd + 2 < n) h[(size_t)(nd + 2) * F_HID + col] = acc2;
    if (nd + 3 < n) h[(size_t)(nd + 3) * F_HID + col] = acc3;
}

// ---------------- layer-1 gather + combine + ReLU ----------------
// wave per node; lane = slot(4) x chunk(16); 4 edges per iteration, float4 loads
__global__ void agg1_kernel(const int* __restrict__ rowstart, const int* __restrict__ csr,
                            const float* __restrict__ dinv, const float* __restrict__ h,
                            const float* __restrict__ b, float* __restrict__ out, int n) {
    int node = blockIdx.x * 4 + (threadIdx.x >> 6);
    int lane = threadIdx.x & 63;
    if (node >= n) return;
    int slot = lane >> 4;        // 0..3
    int c    = lane & 15;        // float4 chunk -> features c*4..c*4+3
    int beg = rowstart[node], end = rowstart[node + 1];
    float4 acc = make_float4(0.f, 0.f, 0.f, 0.f);
    for (int base = beg; base < end; base += 64) {
        int idx = base + lane;
        int   sid = 0; float wgt = 0.f;
        if (idx < end) { sid = csr[idx]; wgt = dinv[sid]; }
        int cnt   = min(64, end - base);
        int iters = (cnt + 3) >> 2;
        for (int j = 0; j < iters; ++j) {
            int   sl = j * 4 + slot;
            int   s  = __shfl(sid, sl);
            float ww = __shfl(wgt, sl);
            float4 hv = *(const float4*)&h[(size_t)s * F_HID + (c << 2)];
            acc.x += hv.x * ww; acc.y += hv.y * ww;
            acc.z += hv.z * ww; acc.w += hv.w * ww;
        }
    }
    float4 t = shfl_xor_f4(acc, 16);
    acc.x += t.x; acc.y += t.y; acc.z += t.z; acc.w += t.w;
    t = shfl_xor_f4(acc, 32);
    acc.x += t.x; acc.y += t.y; acc.z += t.z; acc.w += t.w;
    if (slot == 0) {
        float di = dinv[node];
        float4 hs = *(const float4*)&h[(size_t)node * F_HID + (c << 2)];
        float4 bb = *(const float4*)&b[c << 2];
        float4 v;
        v.x = fmaxf(acc.x * di + hs.x * di * di + bb.x, 0.f);
        v.y = fmaxf(acc.y * di + hs.y * di * di + bb.y, 0.f);
        v.z = fmaxf(acc.z * di + hs.z * di * di + bb.z, 0.f);
        v.w = fmaxf(acc.w * di + hs.w * di * di + bb.w, 0.f);
        *(float4*)&out[(size_t)node * F_HID + (c << 2)] = v;
    }
}

// ---------------- GEMM2: h2[N,40] = out1[N,64] @ W2[64,40] ----------------
__global__ void gemm2_kernel(const float* __restrict__ a, const float* __restrict__ W,
                             float* __restrict__ h, int n) {
    __shared__ float Wl[F_HID * F_OUT];
    int tid = threadIdx.x;
    for (int i = tid; i < F_HID * F_OUT; i += 256) Wl[i] = W[i];
    __syncthreads();
    long long idx = (long long)blockIdx.x * 256 + tid;
    if (idx >= (long long)n * F_OUT) return;
    int node = (int)(idx / F_OUT);
    int col  = (int)(idx - (long long)node * F_OUT);
    const float* arow = a + (size_t)node * F_HID;
    float acc = 0.0f;
    #pragma unroll 8
    for (int k = 0; k < F_HID; ++k)
        acc += arow[k] * Wl[k * F_OUT + col];
    h[idx] = acc;
}

// ---------------- layer-2 gather + combine + log_softmax ----------------
// wave per node; lane = slot(6) x chunk(10); 6 edges per iteration, float4 loads
__global__ void agg2_kernel(const int* __restrict__ rowstart, const int* __restrict__ csr,
                            const float* __restrict__ dinv, const float* __restrict__ h,
                            const float* __restrict__ b, float* __restrict__ out, int n) {
    int node = blockIdx.x * 4 + (threadIdx.x >> 6);
    int lane = threadIdx.x & 63;
    if (node >= n) return;
    int slot = lane / 10;            // 0..6 (lanes 60..63 -> 6, idle slot)
    int c    = lane - slot * 10;     // chunk -> features c*4..c*4+3
    int beg = rowstart[node], end = rowstart[node + 1];
    float4 acc = make_float4(0.f, 0.f, 0.f, 0.f);
    for (int base = beg; base < end; base += 60) {
        int idx = base + lane;
        int   sid = 0; float wgt = 0.f;
        if (lane < 60 && idx < end) { sid = csr[idx]; wgt = dinv[sid]; }
        int cnt   = min(60, end - base);
        int iters = (cnt + 5) / 6;
        for (int j = 0; j < iters; ++j) {
            int   sl = (slot < 6) ? (j * 6 + slot) : 60;   // lane 60 has wgt=0
            int   s  = __shfl(sid, sl);
            float ww = __shfl(wgt, sl);
            float4 hv = *(const float4*)&h[(size_t)s * F_OUT + (c << 2)];
            acc.x += hv.x * ww; acc.y += hv.y * ww;
            acc.z += hv.z * ww; acc.w += hv.w * ww;
        }
    }
    // reduce slots 0..5 (stride 10) into lanes 0..9
    float4 r = acc;
    #pragma unroll
    for (int k = 1; k < 6; ++k) {
        int sl = lane + k * 10;
        r.x += __shfl(acc.x, sl); r.y += __shfl(acc.y, sl);
        r.z += __shfl(acc.z, sl); r.w += __shfl(acc.w, sl);
    }
    float4 val = make_float4(0.f, 0.f, 0.f, 0.f);
    float m = -INFINITY;
    if (lane < 10) {
        float di = dinv[node];
        float4 hs = *(const float4*)&h[(size_t)node * F_OUT + (c << 2)];
        float4 bb = *(const float4*)&b[c << 2];
        val.x = r.x * di + hs.x * di * di + bb.x;
        val.y = r.y * di + hs.y * di * di + bb.y;
        val.z = r.z * di + hs.z * di * di + bb.z;
        val.w = r.w * di + hs.w * di * di + bb.w;
        m = fmaxf(fmaxf(val.x, val.y), fmaxf(val.z, val.w));
    }
    // max/sum across lanes 0..15 group (lanes 10..15 contribute -inf / 0)
    #pragma unroll
    for (int off = 1; off < 16; off <<= 1) m = fmaxf(m, __shfl_xor(m, off));
    float p = 0.f;
    if (lane < 10)
        p = __expf(val.x - m) + __expf(val.y - m) + __expf(val.z - m) + __expf(val.w - m);
    #pragma unroll
    for (int off = 1; off < 16; off <<= 1) p += __shfl_xor(p, off);
    float lse = m + __logf(p);
    if (lane < 10) {
        float4 o;
        o.x = val.x - lse; o.y = val.y - lse; o.z = val.z - lse; o.w = val.w - lse;
        *(float4*)&out[(size_t)node * F_OUT + (c << 2)] = o;
    }
}

extern "C" void kernel_launch(void* const* d_in, const int* in_sizes, int n_in,
                              void* d_out, int out_size, void* d_ws, size_t ws_size,
                              hipStream_t stream) {
    const float* x  = (const float*)d_in[0];
    const int*   ei = (const int*)d_in[1];
    const float* W1 = (const float*)d_in[2];
    const float* b1 = (const float*)d_in[3];
    const float* W2 = (const float*)d_in[4];
    const float* b2 = (const float*)d_in[5];
    const int* src = ei;
    const int* dst = ei + N_EDGES;

    // workspace layout
    char* p = (char*)d_ws;
    int*   hist     = (int*)p;                 p += (size_t)N_NODES * 4;
    int*   local    = (int*)p;                 p += (size_t)N_NODES * 4;
    int*   blocksum = (int*)p;                 p += 512 * 4;
    int*   rowstart = (int*)p;                 p += (size_t)(N_NODES + 4) * 4;
    int*   cursor   = (int*)p;                 p += (size_t)N_NODES * 4;
    int*   csr_src  = (int*)p;                 p += (size_t)N_EDGES * 4;
    float* dinv     = (float*)p;               p += (size_t)N_NODES * 4;
    float* h1       = (float*)p;               p += (size_t)N_NODES * F_HID * 4;
    float* out1     = (float*)p;               p += (size_t)N_NODES * F_HID * 4;
    float* h2       = (float*)p;               p += (size_t)N_NODES * F_OUT * 4;
    float* out      = (float*)d_out;

    hipMemsetAsync(hist, 0, (size_t)N_NODES * 4, stream);

    hist_kernel <<<(N_EDGES + 255) / 256, 256, 0, stream>>>(dst, hist, N_EDGES);
    scan1_kernel<<<SCAN_B, 256, 0, stream>>>(hist, local, blocksum, N_NODES);
    scan2_kernel<<<1, 512, 0, stream>>>(blocksum, SCAN_B);
    scan3_kernel<<<SCAN_B, 256, 0, stream>>>(hist, local, blocksum, rowstart, cursor,
                                             dinv, N_NODES, N_EDGES);
    fill_kernel <<<(N_EDGES + 255) / 256, 256, 0, stream>>>(src, dst, cursor, csr_src, N_EDGES);
    gemm1_kernel<<<(N_NODES + 15) / 16, 256, 0, stream>>>(x, W1, h1, N_NODES);
    agg1_kernel <<<(N_NODES + 3) / 4, 256, 0, stream>>>(rowstart, csr_src, dinv, h1, b1,
                                                        out1, N_NODES);
    gemm2_kernel<<<((N_NODES * F_OUT) + 255) / 256, 256, 0, stream>>>(out1, W2, h2, N_NODES);
    agg2_kernel <<<(N_NODES + 3) / 4, 256, 0, stream>>>(rowstart, csr_src, dinv, h2, b2,
                                                        out, N_NODES);
}

// Round 4
// 397.355 us; speedup vs baseline: 2.4276x; 1.3346x over previous
//
#include <hip/hip_runtime.h>
#include <math.h>

#define N_NODES 100000
#define N_EDGES 1600000
#define F_IN    128
#define F_HID   64
#define F_OUT   40

#define BIN_SHIFT 9
#define NBINS     196          // ceil(100000 / 512)
#define MAX_BIN   10240        // mean 8192, sigma ~90 -> +22 sigma headroom
#define FILL_BLOCKS 256

__device__ __forceinline__ float4 shfl_xor_f4(float4 v, int m) {
    v.x = __shfl_xor(v.x, m); v.y = __shfl_xor(v.y, m);
    v.z = __shfl_xor(v.z, m); v.w = __shfl_xor(v.w, m);
    return v;
}

// ---------------- pass 0: global bin counts (196 bins of 512 nodes) ----------------
__global__ void bincount_kernel(const int* __restrict__ dst, int* __restrict__ bcount, int E) {
    __shared__ int lc[NBINS];
    int tid = threadIdx.x;
    for (int i = tid; i < NBINS; i += 256) lc[i] = 0;
    __syncthreads();
    int chunk = (E + gridDim.x - 1) / gridDim.x;
    int beg = blockIdx.x * chunk, end = min(E, beg + chunk);
    for (int e = beg + tid; e < end; e += 256)
        atomicAdd(&lc[dst[e] >> BIN_SHIFT], 1);
    __syncthreads();
    for (int i = tid; i < NBINS; i += 256)
        if (lc[i]) atomicAdd(&bcount[i], lc[i]);
}

// ---------------- pass 1: scan bin counts -> binstart / bincursor ----------------
__global__ void binscan_kernel(const int* __restrict__ bcount, int* __restrict__ bstart,
                               int* __restrict__ bcursor, int* __restrict__ rowstart) {
    __shared__ int tmp[256];
    int t = threadIdx.x;
    int v = (t < NBINS) ? bcount[t] : 0;
    tmp[t] = v;
    __syncthreads();
    for (int off = 1; off < 256; off <<= 1) {
        int u = (t >= off) ? tmp[t - off] : 0;
        __syncthreads();
        tmp[t] += u;
        __syncthreads();
    }
    if (t < NBINS) { int e = tmp[t] - v; bstart[t] = e; bcursor[t] = e; }
    if (t == 0) { bstart[NBINS] = N_EDGES; rowstart[N_NODES] = N_EDGES; }
}

// ---------------- pass 2: binned scatter of packed (src | ldst<<17) ----------------
__global__ void binfill_kernel(const int* __restrict__ src, const int* __restrict__ dst,
                               int* __restrict__ bcursor, int* __restrict__ bins, int E) {
    __shared__ int lcount[NBINS];
    __shared__ int gbase[NBINS];
    int tid = threadIdx.x;
    for (int i = tid; i < NBINS; i += 256) lcount[i] = 0;
    __syncthreads();
    int chunk = (E + gridDim.x - 1) / gridDim.x;
    int beg = blockIdx.x * chunk, end = min(E, beg + chunk);
    for (int e = beg + tid; e < end; e += 256)
        atomicAdd(&lcount[dst[e] >> BIN_SHIFT], 1);
    __syncthreads();
    for (int i = tid; i < NBINS; i += 256) {
        gbase[i] = lcount[i] ? atomicAdd(&bcursor[i], lcount[i]) : 0;
        lcount[i] = 0;
    }
    __syncthreads();
    for (int e = beg + tid; e < end; e += 256) {
        int d = dst[e];
        int b = d >> BIN_SHIFT;
        int p = atomicAdd(&lcount[b], 1);
        bins[gbase[b] + p] = src[e] | ((d & 511) << 17);
    }
}

// ---------------- pass 3: per-bin counting sort; emits rowstart/dinv/csr ----------
__global__ void binsort_kernel(const int* __restrict__ bstart, const int* __restrict__ bins,
                               int* __restrict__ csr, int* __restrict__ rowstart,
                               float* __restrict__ dinv) {
    __shared__ int hist[512];
    __shared__ int scan[512];
    __shared__ int cur[512];
    __shared__ int sorted[MAX_BIN];
    int b = blockIdx.x, t = threadIdx.x;
    int base = bstart[b], cnt = bstart[b + 1] - base;
    hist[t] = 0;
    __syncthreads();
    for (int i = t; i < cnt; i += 512)
        atomicAdd(&hist[(unsigned)bins[base + i] >> 17], 1);
    __syncthreads();
    int v = hist[t];
    scan[t] = v;
    __syncthreads();
    for (int off = 1; off < 512; off <<= 1) {
        int u = (t >= off) ? scan[t - off] : 0;
        __syncthreads();
        scan[t] += u;
        __syncthreads();
    }
    int excl = scan[t] - v;
    cur[t] = excl;
    int node = (b << BIN_SHIFT) + t;
    if (node < N_NODES) {
        rowstart[node] = base + excl;
        dinv[node] = rsqrtf((float)v + 1.0f);   // +1 self-loop
    }
    __syncthreads();
    for (int i = t; i < cnt; i += 512) {
        int p   = bins[base + i];
        int pos = atomicAdd(&cur[(unsigned)p >> 17], 1);
        sorted[pos] = p & 0x1FFFF;
    }
    __syncthreads();
    for (int i = t; i < cnt; i += 512)
        csr[base + i] = sorted[i];
}

// ---------------- GEMM1: h1[N,64] = x[N,128] @ W1[128,64] ----------------
__global__ void gemm1_kernel(const float* __restrict__ x, const float* __restrict__ W,
                             float* __restrict__ h, int n) {
    __shared__ float Wl[F_IN * F_HID];   // 32 KB
    __shared__ float Xl[16 * F_IN];      // 8 KB
    int tid = threadIdx.x;
    for (int i = tid; i < F_IN * F_HID; i += 256) Wl[i] = W[i];
    int node0 = blockIdx.x * 16;
    for (int i = tid; i < 16 * F_IN; i += 256) {
        int nd = node0 + (i >> 7);
        Xl[i] = (nd < n) ? x[(size_t)nd * F_IN + (i & (F_IN - 1))] : 0.0f;
    }
    __syncthreads();
    int w   = tid >> 6;
    int col = tid & 63;
    int r0  = w * 4;
    float acc0 = 0.f, acc1 = 0.f, acc2 = 0.f, acc3 = 0.f;
    #pragma unroll 4
    for (int k0 = 0; k0 < F_IN; k0 += 4) {
        float4 xv0 = *(const float4*)&Xl[(r0 + 0) * F_IN + k0];
        float4 xv1 = *(const float4*)&Xl[(r0 + 1) * F_IN + k0];
        float4 xv2 = *(const float4*)&Xl[(r0 + 2) * F_IN + k0];
        float4 xv3 = *(const float4*)&Xl[(r0 + 3) * F_IN + k0];
        float w0 = Wl[(k0 + 0) * F_HID + col];
        float w1 = Wl[(k0 + 1) * F_HID + col];
        float w2 = Wl[(k0 + 2) * F_HID + col];
        float w3 = Wl[(k0 + 3) * F_HID + col];
        acc0 += xv0.x * w0 + xv0.y * w1 + xv0.z * w2 + xv0.w * w3;
        acc1 += xv1.x * w0 + xv1.y * w1 + xv1.z * w2 + xv1.w * w3;
        acc2 += xv2.x * w0 + xv2.y * w1 + xv2.z * w2 + xv2.w * w3;
        acc3 += xv3.x * w0 + xv3.y * w1 + xv3.z * w2 + xv3.w * w3;
    }
    int nd = node0 + r0;
    if (nd + 0 < n) h[(size_t)(nd + 0) * F_HID + col] = acc0;
    if (nd + 1 < n) h[(size_t)(nd + 1) * F_HID + col] = acc1;
    if (nd + 2 < n) h[(size_t)(nd + 2) * F_HID + col] = acc2;
    if (nd + 3 < n) h[(size_t)(nd + 3) * F_HID + col] = acc3;
}

// ---------------- layer-1 gather + combine + ReLU ----------------
__global__ void agg1_kernel(const int* __restrict__ rowstart, const int* __restrict__ csr,
                            const float* __restrict__ dinv, const float* __restrict__ h,
                            const float* __restrict__ b, float* __restrict__ out, int n) {
    int node = blockIdx.x * 4 + (threadIdx.x >> 6);
    int lane = threadIdx.x & 63;
    if (node >= n) return;
    int slot = lane >> 4;
    int c    = lane & 15;
    int beg = rowstart[node], end = rowstart[node + 1];
    float4 acc = make_float4(0.f, 0.f, 0.f, 0.f);
    for (int base = beg; base < end; base += 64) {
        int idx = base + lane;
        int   sid = 0; float wgt = 0.f;
        if (idx < end) { sid = csr[idx]; wgt = dinv[sid]; }
        int cnt   = min(64, end - base);
        int iters = (cnt + 3) >> 2;
        for (int j = 0; j < iters; ++j) {
            int   sl = j * 4 + slot;
            int   s  = __shfl(sid, sl);
            float ww = __shfl(wgt, sl);
            float4 hv = *(const float4*)&h[(size_t)s * F_HID + (c << 2)];
            acc.x += hv.x * ww; acc.y += hv.y * ww;
            acc.z += hv.z * ww; acc.w += hv.w * ww;
        }
    }
    float4 t = shfl_xor_f4(acc, 16);
    acc.x += t.x; acc.y += t.y; acc.z += t.z; acc.w += t.w;
    t = shfl_xor_f4(acc, 32);
    acc.x += t.x; acc.y += t.y; acc.z += t.z; acc.w += t.w;
    if (slot == 0) {
        float di = dinv[node];
        float4 hs = *(const float4*)&h[(size_t)node * F_HID + (c << 2)];
        float4 bb = *(const float4*)&b[c << 2];
        float4 v;
        v.x = fmaxf(acc.x * di + hs.x * di * di + bb.x, 0.f);
        v.y = fmaxf(acc.y * di + hs.y * di * di + bb.y, 0.f);
        v.z = fmaxf(acc.z * di + hs.z * di * di + bb.z, 0.f);
        v.w = fmaxf(acc.w * di + hs.w * di * di + bb.w, 0.f);
        *(float4*)&out[(size_t)node * F_HID + (c << 2)] = v;
    }
}

// ---------------- GEMM2: h2[N,40] = out1[N,64] @ W2[64,40] ----------------
__global__ void gemm2_kernel(const float* __restrict__ a, const float* __restrict__ W,
                             float* __restrict__ h, int n) {
    __shared__ float Wl[F_HID * F_OUT];
    int tid = threadIdx.x;
    for (int i = tid; i < F_HID * F_OUT; i += 256) Wl[i] = W[i];
    __syncthreads();
    long long idx = (long long)blockIdx.x * 256 + tid;
    if (idx >= (long long)n * F_OUT) return;
    int node = (int)(idx / F_OUT);
    int col  = (int)(idx - (long long)node * F_OUT);
    const float* arow = a + (size_t)node * F_HID;
    float acc = 0.0f;
    #pragma unroll 8
    for (int k = 0; k < F_HID; ++k)
        acc += arow[k] * Wl[k * F_OUT + col];
    h[idx] = acc;
}

// ---------------- layer-2 gather + combine + log_softmax ----------------
__global__ void agg2_kernel(const int* __restrict__ rowstart, const int* __restrict__ csr,
                            const float* __restrict__ dinv, const float* __restrict__ h,
                            const float* __restrict__ b, float* __restrict__ out, int n) {
    int node = blockIdx.x * 4 + (threadIdx.x >> 6);
    int lane = threadIdx.x & 63;
    if (node >= n) return;
    int slot = lane / 10;
    int c    = lane - slot * 10;
    int beg = rowstart[node], end = rowstart[node + 1];
    float4 acc = make_float4(0.f, 0.f, 0.f, 0.f);
    for (int base = beg; base < end; base += 60) {
        int idx = base + lane;
        int   sid = 0; float wgt = 0.f;
        if (lane < 60 && idx < end) { sid = csr[idx]; wgt = dinv[sid]; }
        int cnt   = min(60, end - base);
        int iters = (cnt + 5) / 6;
        for (int j = 0; j < iters; ++j) {
            int   sl = (slot < 6) ? (j * 6 + slot) : 60;
            int   s  = __shfl(sid, sl);
            float ww = __shfl(wgt, sl);
            float4 hv = *(const float4*)&h[(size_t)s * F_OUT + (c << 2)];
            acc.x += hv.x * ww; acc.y += hv.y * ww;
            acc.z += hv.z * ww; acc.w += hv.w * ww;
        }
    }
    float4 r = acc;
    #pragma unroll
    for (int k = 1; k < 6; ++k) {
        int sl = lane + k * 10;
        r.x += __shfl(acc.x, sl); r.y += __shfl(acc.y, sl);
        r.z += __shfl(acc.z, sl); r.w += __shfl(acc.w, sl);
    }
    float4 val = make_float4(0.f, 0.f, 0.f, 0.f);
    float m = -INFINITY;
    if (lane < 10) {
        float di = dinv[node];
        float4 hs = *(const float4*)&h[(size_t)node * F_OUT + (c << 2)];
        float4 bb = *(const float4*)&b[c << 2];
        val.x = r.x * di + hs.x * di * di + bb.x;
        val.y = r.y * di + hs.y * di * di + bb.y;
        val.z = r.z * di + hs.z * di * di + bb.z;
        val.w = r.w * di + hs.w * di * di + bb.w;
        m = fmaxf(fmaxf(val.x, val.y), fmaxf(val.z, val.w));
    }
    #pragma unroll
    for (int off = 1; off < 16; off <<= 1) m = fmaxf(m, __shfl_xor(m, off));
    float p = 0.f;
    if (lane < 10)
        p = __expf(val.x - m) + __expf(val.y - m) + __expf(val.z - m) + __expf(val.w - m);
    #pragma unroll
    for (int off = 1; off < 16; off <<= 1) p += __shfl_xor(p, off);
    float lse = m + __logf(p);
    if (lane < 10) {
        float4 o;
        o.x = val.x - lse; o.y = val.y - lse; o.z = val.z - lse; o.w = val.w - lse;
        *(float4*)&out[(size_t)node * F_OUT + (c << 2)] = o;
    }
}

extern "C" void kernel_launch(void* const* d_in, const int* in_sizes, int n_in,
                              void* d_out, int out_size, void* d_ws, size_t ws_size,
                              hipStream_t stream) {
    const float* x  = (const float*)d_in[0];
    const int*   ei = (const int*)d_in[1];
    const float* W1 = (const float*)d_in[2];
    const float* b1 = (const float*)d_in[3];
    const float* W2 = (const float*)d_in[4];
    const float* b2 = (const float*)d_in[5];
    const int* src = ei;
    const int* dst = ei + N_EDGES;

    // workspace layout
    char* p = (char*)d_ws;
    int*   bcount   = (int*)p;                 p += (size_t)(NBINS + 4) * 4;
    int*   bstart   = (int*)p;                 p += (size_t)(NBINS + 4) * 4;
    int*   bcursor  = (int*)p;                 p += (size_t)(NBINS + 4) * 4;
    int*   bins     = (int*)p;                 p += (size_t)N_EDGES * 4;
    int*   csr_src  = (int*)p;                 p += (size_t)N_EDGES * 4;
    int*   rowstart = (int*)p;                 p += (size_t)(N_NODES + 4) * 4;
    float* dinv     = (float*)p;               p += (size_t)N_NODES * 4;
    float* h1       = (float*)p;               p += (size_t)N_NODES * F_HID * 4;
    float* out1     = (float*)p;               p += (size_t)N_NODES * F_HID * 4;
    float* h2       = (float*)p;               p += (size_t)N_NODES * F_OUT * 4;
    float* out      = (float*)d_out;

    hipMemsetAsync(bcount, 0, (size_t)NBINS * 4, stream);

    bincount_kernel<<<FILL_BLOCKS, 256, 0, stream>>>(dst, bcount, N_EDGES);
    binscan_kernel <<<1, 256, 0, stream>>>(bcount, bstart, bcursor, rowstart);
    binfill_kernel <<<FILL_BLOCKS, 256, 0, stream>>>(src, dst, bcursor, bins, N_EDGES);
    binsort_kernel <<<NBINS, 512, 0, stream>>>(bstart, bins, csr_src, rowstart, dinv);
    gemm1_kernel<<<(N_NODES + 15) / 16, 256, 0, stream>>>(x, W1, h1, N_NODES);
    agg1_kernel <<<(N_NODES + 3) / 4, 256, 0, stream>>>(rowstart, csr_src, dinv, h1, b1,
                                                        out1, N_NODES);
    gemm2_kernel<<<((N_NODES * F_OUT) + 255) / 256, 256, 0, stream>>>(out1, W2, h2, N_NODES);
    agg2_kernel <<<(N_NODES + 3) / 4, 256, 0, stream>>>(rowstart, csr_src, dinv, h2, b2,
                                                        out, N_NODES);
}

// Round 5
// 347.837 us; speedup vs baseline: 2.7731x; 1.1424x over previous
//
#include <hip/hip_runtime.h>
#include <math.h>

#define N_NODES 100000
#define N_EDGES 1600000
#define F_IN    128
#define F_HID   64
#define F_OUT   40

#define BIN_SHIFT 9
#define NBINS     196          // ceil(100000 / 512)
#define MAX_BIN   10240
#define FILL_BLOCKS 256

typedef unsigned int  uint;
typedef unsigned short ushort;

__device__ __forceinline__ unsigned short f2bf(float f) {      // RNE, finite inputs
    uint u = __float_as_uint(f);
    u = (u + 0x7FFF + ((u >> 16) & 1)) >> 16;
    return (unsigned short)u;
}
__device__ __forceinline__ float bf_lo(uint u) { return __uint_as_float(u << 16); }
__device__ __forceinline__ float bf_hi(uint u) { return __uint_as_float(u & 0xFFFF0000u); }

// ---------------- pass 0: global bin counts ----------------
__global__ void bincount_kernel(const int* __restrict__ dst, int* __restrict__ bcount, int E) {
    __shared__ int lc[NBINS];
    int tid = threadIdx.x;
    for (int i = tid; i < NBINS; i += 256) lc[i] = 0;
    __syncthreads();
    int chunk = (E + gridDim.x - 1) / gridDim.x;
    int beg = blockIdx.x * chunk, end = min(E, beg + chunk);
    for (int e = beg + tid; e < end; e += 256)
        atomicAdd(&lc[dst[e] >> BIN_SHIFT], 1);
    __syncthreads();
    for (int i = tid; i < NBINS; i += 256)
        if (lc[i]) atomicAdd(&bcount[i], lc[i]);
}

// ---------------- pass 1: scan bin counts ----------------
__global__ void binscan_kernel(const int* __restrict__ bcount, int* __restrict__ bstart,
                               int* __restrict__ bcursor, int* __restrict__ rowstart) {
    __shared__ int tmp[256];
    int t = threadIdx.x;
    int v = (t < NBINS) ? bcount[t] : 0;
    tmp[t] = v;
    __syncthreads();
    for (int off = 1; off < 256; off <<= 1) {
        int u = (t >= off) ? tmp[t - off] : 0;
        __syncthreads();
        tmp[t] += u;
        __syncthreads();
    }
    if (t < NBINS) { int e = tmp[t] - v; bstart[t] = e; bcursor[t] = e; }
    if (t == 0) { bstart[NBINS] = N_EDGES; rowstart[N_NODES] = N_EDGES; }
}

// ---------------- pass 2: binned scatter of packed (src | ldst<<17) ----------------
__global__ void binfill_kernel(const int* __restrict__ src, const int* __restrict__ dst,
                               int* __restrict__ bcursor, int* __restrict__ bins, int E) {
    __shared__ int lcount[NBINS];
    __shared__ int gbase[NBINS];
    int tid = threadIdx.x;
    for (int i = tid; i < NBINS; i += 256) lcount[i] = 0;
    __syncthreads();
    int chunk = (E + gridDim.x - 1) / gridDim.x;
    int beg = blockIdx.x * chunk, end = min(E, beg + chunk);
    for (int e = beg + tid; e < end; e += 256)
        atomicAdd(&lcount[dst[e] >> BIN_SHIFT], 1);
    __syncthreads();
    for (int i = tid; i < NBINS; i += 256) {
        gbase[i] = lcount[i] ? atomicAdd(&bcursor[i], lcount[i]) : 0;
        lcount[i] = 0;
    }
    __syncthreads();
    for (int e = beg + tid; e < end; e += 256) {
        int d = dst[e];
        int b = d >> BIN_SHIFT;
        int p = atomicAdd(&lcount[b], 1);
        bins[gbase[b] + p] = src[e] | ((d & 511) << 17);
    }
}

// ---------------- pass 3: per-bin counting sort ----------------
__global__ void binsort_kernel(const int* __restrict__ bstart, const int* __restrict__ bins,
                               int* __restrict__ csr, int* __restrict__ rowstart,
                               float* __restrict__ dinv) {
    __shared__ int hist[512];
    __shared__ int scan[512];
    __shared__ int cur[512];
    __shared__ int sorted[MAX_BIN];
    int b = blockIdx.x, t = threadIdx.x;
    int base = bstart[b], cnt = bstart[b + 1] - base;
    hist[t] = 0;
    __syncthreads();
    for (int i = t; i < cnt; i += 512)
        atomicAdd(&hist[(unsigned)bins[base + i] >> 17], 1);
    __syncthreads();
    int v = hist[t];
    scan[t] = v;
    __syncthreads();
    for (int off = 1; off < 512; off <<= 1) {
        int u = (t >= off) ? scan[t - off] : 0;
        __syncthreads();
        scan[t] += u;
        __syncthreads();
    }
    int excl = scan[t] - v;
    cur[t] = excl;
    int node = (b << BIN_SHIFT) + t;
    if (node < N_NODES) {
        rowstart[node] = base + excl;
        dinv[node] = rsqrtf((float)v + 1.0f);
    }
    __syncthreads();
    for (int i = t; i < cnt; i += 512) {
        int p   = bins[base + i];
        int pos = atomicAdd(&cur[(unsigned)p >> 17], 1);
        sorted[pos] = p & 0x1FFFF;
    }
    __syncthreads();
    for (int i = t; i < cnt; i += 512)
        csr[base + i] = sorted[i];
}

// ---------------- GEMM1: h1b[N,64](bf16) = x[N,128] @ W1[128,64] ----------------
__global__ void gemm1_kernel(const float* __restrict__ x, const float* __restrict__ W,
                             ushort* __restrict__ h, int n) {
    __shared__ float Wl[F_IN * F_HID];
    __shared__ float Xl[16 * F_IN];
    int tid = threadIdx.x;
    for (int i = tid; i < F_IN * F_HID; i += 256) Wl[i] = W[i];
    int node0 = blockIdx.x * 16;
    for (int i = tid; i < 16 * F_IN; i += 256) {
        int nd = node0 + (i >> 7);
        Xl[i] = (nd < n) ? x[(size_t)nd * F_IN + (i & (F_IN - 1))] : 0.0f;
    }
    __syncthreads();
    int w   = tid >> 6;
    int col = tid & 63;
    int r0  = w * 4;
    float acc0 = 0.f, acc1 = 0.f, acc2 = 0.f, acc3 = 0.f;
    #pragma unroll 4
    for (int k0 = 0; k0 < F_IN; k0 += 4) {
        float4 xv0 = *(const float4*)&Xl[(r0 + 0) * F_IN + k0];
        float4 xv1 = *(const float4*)&Xl[(r0 + 1) * F_IN + k0];
        float4 xv2 = *(const float4*)&Xl[(r0 + 2) * F_IN + k0];
        float4 xv3 = *(const float4*)&Xl[(r0 + 3) * F_IN + k0];
        float w0 = Wl[(k0 + 0) * F_HID + col];
        float w1 = Wl[(k0 + 1) * F_HID + col];
        float w2 = Wl[(k0 + 2) * F_HID + col];
        float w3 = Wl[(k0 + 3) * F_HID + col];
        acc0 += xv0.x * w0 + xv0.y * w1 + xv0.z * w2 + xv0.w * w3;
        acc1 += xv1.x * w0 + xv1.y * w1 + xv1.z * w2 + xv1.w * w3;
        acc2 += xv2.x * w0 + xv2.y * w1 + xv2.z * w2 + xv2.w * w3;
        acc3 += xv3.x * w0 + xv3.y * w1 + xv3.z * w2 + xv3.w * w3;
    }
    int nd = node0 + r0;
    if (nd + 0 < n) h[(size_t)(nd + 0) * F_HID + col] = f2bf(acc0);
    if (nd + 1 < n) h[(size_t)(nd + 1) * F_HID + col] = f2bf(acc1);
    if (nd + 2 < n) h[(size_t)(nd + 2) * F_HID + col] = f2bf(acc2);
    if (nd + 3 < n) h[(size_t)(nd + 3) * F_HID + col] = f2bf(acc3);
}

// ---------------- layer-1 gather + combine + ReLU (bf16 rows, 8 edges/iter) -------
__global__ void agg1_kernel(const int* __restrict__ rowstart, const int* __restrict__ csr,
                            const float* __restrict__ dinv, const ushort* __restrict__ h,
                            const float* __restrict__ b, ushort* __restrict__ out, int n) {
    int node = blockIdx.x * 4 + (threadIdx.x >> 6);
    int lane = threadIdx.x & 63;
    if (node >= n) return;
    int slot = lane >> 3;        // 0..7
    int c    = lane & 7;         // chunk -> features c*8 .. c*8+7
    int beg = rowstart[node], end = rowstart[node + 1];
    float acc[8] = {0.f,0.f,0.f,0.f,0.f,0.f,0.f,0.f};
    for (int base = beg; base < end; base += 64) {
        int idx = base + lane;
        int   sid = 0; float wgt = 0.f;
        if (idx < end) { sid = csr[idx]; wgt = dinv[sid]; }
        int cnt   = min(64, end - base);
        int iters = (cnt + 7) >> 3;
        for (int j = 0; j < iters; ++j) {
            int   sl = j * 8 + slot;
            int   s  = __shfl(sid, sl);
            float ww = __shfl(wgt, sl);
            uint4 hv = *(const uint4*)&h[(size_t)s * F_HID + (c << 3)];
            acc[0] += bf_lo(hv.x) * ww; acc[1] += bf_hi(hv.x) * ww;
            acc[2] += bf_lo(hv.y) * ww; acc[3] += bf_hi(hv.y) * ww;
            acc[4] += bf_lo(hv.z) * ww; acc[5] += bf_hi(hv.z) * ww;
            acc[6] += bf_lo(hv.w) * ww; acc[7] += bf_hi(hv.w) * ww;
        }
    }
    #pragma unroll
    for (int m = 8; m < 64; m <<= 1) {
        #pragma unroll
        for (int k = 0; k < 8; ++k) acc[k] += __shfl_xor(acc[k], m);
    }
    if (slot == 0) {
        float di = dinv[node];
        uint4 hs = *(const uint4*)&h[(size_t)node * F_HID + (c << 3)];
        float self[8] = { bf_lo(hs.x), bf_hi(hs.x), bf_lo(hs.y), bf_hi(hs.y),
                          bf_lo(hs.z), bf_hi(hs.z), bf_lo(hs.w), bf_hi(hs.w) };
        float4 b0 = *(const float4*)&b[c << 3];
        float4 b1v = *(const float4*)&b[(c << 3) + 4];
        float bb[8] = { b0.x, b0.y, b0.z, b0.w, b1v.x, b1v.y, b1v.z, b1v.w };
        ushort o[8];
        #pragma unroll
        for (int k = 0; k < 8; ++k) {
            float v = fmaxf(acc[k] * di + self[k] * di * di + bb[k], 0.f);
            o[k] = f2bf(v);
        }
        uint4 pk;
        pk.x = (uint)o[0] | ((uint)o[1] << 16);
        pk.y = (uint)o[2] | ((uint)o[3] << 16);
        pk.z = (uint)o[4] | ((uint)o[5] << 16);
        pk.w = (uint)o[6] | ((uint)o[7] << 16);
        *(uint4*)&out[(size_t)node * F_HID + (c << 3)] = pk;
    }
}

// ---------------- GEMM2: h2b[N,40](bf16) = out1b[N,64](bf16) @ W2[64,40] ----------
__global__ void gemm2_kernel(const ushort* __restrict__ a, const float* __restrict__ W,
                             ushort* __restrict__ h, int n) {
    __shared__ float Wl[F_HID * F_OUT];
    int tid = threadIdx.x;
    for (int i = tid; i < F_HID * F_OUT; i += 256) Wl[i] = W[i];
    __syncthreads();
    long long idx = (long long)blockIdx.x * 256 + tid;
    if (idx >= (long long)n * F_OUT) return;
    int node = (int)(idx / F_OUT);
    int col  = (int)(idx - (long long)node * F_OUT);
    const uint* arow = (const uint*)(a + (size_t)node * F_HID);
    float acc = 0.0f;
    #pragma unroll 8
    for (int k = 0; k < F_HID / 2; ++k) {
        uint u = arow[k];
        acc += bf_lo(u) * Wl[(2 * k) * F_OUT + col] + bf_hi(u) * Wl[(2 * k + 1) * F_OUT + col];
    }
    h[idx] = f2bf(acc);
}

// ---------------- layer-2 gather + combine + log_softmax (bf16 rows) --------------
__global__ void agg2_kernel(const int* __restrict__ rowstart, const int* __restrict__ csr,
                            const float* __restrict__ dinv, const ushort* __restrict__ h,
                            const float* __restrict__ b, float* __restrict__ out, int n) {
    int node = blockIdx.x * 4 + (threadIdx.x >> 6);
    int lane = threadIdx.x & 63;
    if (node >= n) return;
    int slot = lane / 10;            // 0..6 (lanes 60..63 idle slot)
    int c    = lane - slot * 10;     // chunk -> features c*4..c*4+3
    int beg = rowstart[node], end = rowstart[node + 1];
    float acc[4] = {0.f, 0.f, 0.f, 0.f};
    for (int base = beg; base < end; base += 60) {
        int idx = base + lane;
        int   sid = 0; float wgt = 0.f;
        if (lane < 60 && idx < end) { sid = csr[idx]; wgt = dinv[sid]; }
        int cnt   = min(60, end - base);
        int iters = (cnt + 5) / 6;
        for (int j = 0; j < iters; ++j) {
            int   sl = (slot < 6) ? (j * 6 + slot) : 60;
            int   s  = __shfl(sid, sl);
            float ww = __shfl(wgt, sl);
            uint2 hv = *(const uint2*)&h[(size_t)s * F_OUT + (c << 2)];
            acc[0] += bf_lo(hv.x) * ww; acc[1] += bf_hi(hv.x) * ww;
            acc[2] += bf_lo(hv.y) * ww; acc[3] += bf_hi(hv.y) * ww;
        }
    }
    float r[4] = { acc[0], acc[1], acc[2], acc[3] };
    #pragma unroll
    for (int k = 1; k < 6; ++k) {
        int sl = lane + k * 10;
        r[0] += __shfl(acc[0], sl); r[1] += __shfl(acc[1], sl);
        r[2] += __shfl(acc[2], sl); r[3] += __shfl(acc[3], sl);
    }
    float val[4] = {0.f, 0.f, 0.f, 0.f};
    float m = -INFINITY;
    if (lane < 10) {
        float di = dinv[node];
        uint2 hs = *(const uint2*)&h[(size_t)node * F_OUT + (c << 2)];
        float self[4] = { bf_lo(hs.x), bf_hi(hs.x), bf_lo(hs.y), bf_hi(hs.y) };
        float4 bb = *(const float4*)&b[c << 2];
        float bbv[4] = { bb.x, bb.y, bb.z, bb.w };
        #pragma unroll
        for (int k = 0; k < 4; ++k) {
            val[k] = r[k] * di + self[k] * di * di + bbv[k];
            m = fmaxf(m, val[k]);
        }
    }
    #pragma unroll
    for (int off = 1; off < 16; off <<= 1) m = fmaxf(m, __shfl_xor(m, off));
    float p = 0.f;
    if (lane < 10)
        p = __expf(val[0] - m) + __expf(val[1] - m) + __expf(val[2] - m) + __expf(val[3] - m);
    #pragma unroll
    for (int off = 1; off < 16; off <<= 1) p += __shfl_xor(p, off);
    float lse = m + __logf(p);
    if (lane < 10) {
        float4 o;
        o.x = val[0] - lse; o.y = val[1] - lse; o.z = val[2] - lse; o.w = val[3] - lse;
        *(float4*)&out[(size_t)node * F_OUT + (c << 2)] = o;
    }
}

extern "C" void kernel_launch(void* const* d_in, const int* in_sizes, int n_in,
                              void* d_out, int out_size, void* d_ws, size_t ws_size,
                              hipStream_t stream) {
    const float* x  = (const float*)d_in[0];
    const int*   ei = (const int*)d_in[1];
    const float* W1 = (const float*)d_in[2];
    const float* b1 = (const float*)d_in[3];
    const float* W2 = (const float*)d_in[4];
    const float* b2 = (const float*)d_in[5];
    const int* src = ei;
    const int* dst = ei + N_EDGES;

    // workspace layout (all chunks 16B-aligned)
    char* p = (char*)d_ws;
    int*    bcount   = (int*)p;     p += (size_t)(NBINS + 4) * 4;
    int*    bstart   = (int*)p;     p += (size_t)(NBINS + 4) * 4;
    int*    bcursor  = (int*)p;     p += (size_t)(NBINS + 4) * 4;
    int*    bins     = (int*)p;     p += (size_t)N_EDGES * 4;
    int*    csr_src  = (int*)p;     p += (size_t)N_EDGES * 4;
    int*    rowstart = (int*)p;     p += (size_t)(N_NODES + 4) * 4;
    float*  dinv     = (float*)p;   p += (size_t)N_NODES * 4;
    ushort* h1b      = (ushort*)p;  p += (size_t)N_NODES * F_HID * 2;
    ushort* out1b    = (ushort*)p;  p += (size_t)N_NODES * F_HID * 2;
    ushort* h2b      = (ushort*)p;  p += (size_t)N_NODES * F_OUT * 2;
    float*  out      = (float*)d_out;

    hipMemsetAsync(bcount, 0, (size_t)NBINS * 4, stream);

    bincount_kernel<<<FILL_BLOCKS, 256, 0, stream>>>(dst, bcount, N_EDGES);
    binscan_kernel <<<1, 256, 0, stream>>>(bcount, bstart, bcursor, rowstart);
    binfill_kernel <<<FILL_BLOCKS, 256, 0, stream>>>(src, dst, bcursor, bins, N_EDGES);
    binsort_kernel <<<NBINS, 512, 0, stream>>>(bstart, bins, csr_src, rowstart, dinv);
    gemm1_kernel<<<(N_NODES + 15) / 16, 256, 0, stream>>>(x, W1, h1b, N_NODES);
    agg1_kernel <<<(N_NODES + 3) / 4, 256, 0, stream>>>(rowstart, csr_src, dinv, h1b, b1,
                                                        out1b, N_NODES);
    gemm2_kernel<<<((N_NODES * F_OUT) + 255) / 256, 256, 0, stream>>>(out1b, W2, h2b, N_NODES);
    agg2_kernel <<<(N_NODES + 3) / 4, 256, 0, stream>>>(rowstart, csr_src, dinv, h2b, b2,
                                                        out, N_NODES);
}

// Round 6
// 342.272 us; speedup vs baseline: 2.8182x; 1.0163x over previous
//
#include <hip/hip_runtime.h>
#include <math.h>

#define N_NODES 100000
#define N_EDGES 1600000
#define F_IN    128
#define F_HID   64
#define F_OUT   40

#define BIN_SHIFT 9
#define NBINS     196          // ceil(100000 / 512)
#define MAX_BIN   10240
#define FILL_BLOCKS 256

typedef unsigned int  uint;
typedef unsigned short ushort;

__device__ __forceinline__ unsigned short f2bf(float f) {      // RNE, finite inputs
    uint u = __float_as_uint(f);
    u = (u + 0x7FFF + ((u >> 16) & 1)) >> 16;
    return (unsigned short)u;
}
__device__ __forceinline__ float bf_lo(uint u) { return __uint_as_float(u << 16); }
__device__ __forceinline__ float bf_hi(uint u) { return __uint_as_float(u & 0xFFFF0000u); }

// ---------------- pass 0: global bin counts ----------------
__global__ void bincount_kernel(const int* __restrict__ dst, int* __restrict__ bcount, int E) {
    __shared__ int lc[NBINS];
    int tid = threadIdx.x;
    for (int i = tid; i < NBINS; i += 256) lc[i] = 0;
    __syncthreads();
    int chunk = (E + gridDim.x - 1) / gridDim.x;
    int beg = blockIdx.x * chunk, end = min(E, beg + chunk);
    for (int e = beg + tid; e < end; e += 256)
        atomicAdd(&lc[dst[e] >> BIN_SHIFT], 1);
    __syncthreads();
    for (int i = tid; i < NBINS; i += 256)
        if (lc[i]) atomicAdd(&bcount[i], lc[i]);
}

// ---------------- pass 1: scan bin counts ----------------
__global__ void binscan_kernel(const int* __restrict__ bcount, int* __restrict__ bstart,
                               int* __restrict__ bcursor, int* __restrict__ rowstart) {
    __shared__ int tmp[256];
    int t = threadIdx.x;
    int v = (t < NBINS) ? bcount[t] : 0;
    tmp[t] = v;
    __syncthreads();
    for (int off = 1; off < 256; off <<= 1) {
        int u = (t >= off) ? tmp[t - off] : 0;
        __syncthreads();
        tmp[t] += u;
        __syncthreads();
    }
    if (t < NBINS) { int e = tmp[t] - v; bstart[t] = e; bcursor[t] = e; }
    if (t == 0) { bstart[NBINS] = N_EDGES; rowstart[N_NODES] = N_EDGES; }
}

// ---------------- pass 2: binned scatter of packed (src | ldst<<17) ----------------
__global__ void binfill_kernel(const int* __restrict__ src, const int* __restrict__ dst,
                               int* __restrict__ bcursor, int* __restrict__ bins, int E) {
    __shared__ int lcount[NBINS];
    __shared__ int gbase[NBINS];
    int tid = threadIdx.x;
    for (int i = tid; i < NBINS; i += 256) lcount[i] = 0;
    __syncthreads();
    int chunk = (E + gridDim.x - 1) / gridDim.x;
    int beg = blockIdx.x * chunk, end = min(E, beg + chunk);
    for (int e = beg + tid; e < end; e += 256)
        atomicAdd(&lcount[dst[e] >> BIN_SHIFT], 1);
    __syncthreads();
    for (int i = tid; i < NBINS; i += 256) {
        gbase[i] = lcount[i] ? atomicAdd(&bcursor[i], lcount[i]) : 0;
        lcount[i] = 0;
    }
    __syncthreads();
    for (int e = beg + tid; e < end; e += 256) {
        int d = dst[e];
        int b = d >> BIN_SHIFT;
        int p = atomicAdd(&lcount[b], 1);
        bins[gbase[b] + p] = src[e] | ((d & 511) << 17);
    }
}

// ---------------- pass 3: per-bin counting sort ----------------
__global__ void binsort_kernel(const int* __restrict__ bstart, const int* __restrict__ bins,
                               int* __restrict__ csr, int* __restrict__ rowstart,
                               float* __restrict__ dinv) {
    __shared__ int hist[512];
    __shared__ int scan[512];
    __shared__ int cur[512];
    __shared__ int sorted[MAX_BIN];
    int b = blockIdx.x, t = threadIdx.x;
    int base = bstart[b], cnt = bstart[b + 1] - base;
    hist[t] = 0;
    __syncthreads();
    for (int i = t; i < cnt; i += 512)
        atomicAdd(&hist[(unsigned)bins[base + i] >> 17], 1);
    __syncthreads();
    int v = hist[t];
    scan[t] = v;
    __syncthreads();
    for (int off = 1; off < 512; off <<= 1) {
        int u = (t >= off) ? scan[t - off] : 0;
        __syncthreads();
        scan[t] += u;
        __syncthreads();
    }
    int excl = scan[t] - v;
    cur[t] = excl;
    int node = (b << BIN_SHIFT) + t;
    if (node < N_NODES) {
        rowstart[node] = base + excl;
        dinv[node] = rsqrtf((float)v + 1.0f);
    }
    __syncthreads();
    for (int i = t; i < cnt; i += 512) {
        int p   = bins[base + i];
        int pos = atomicAdd(&cur[(unsigned)p >> 17], 1);
        sorted[pos] = p & 0x1FFFF;
    }
    __syncthreads();
    for (int i = t; i < cnt; i += 512)
        csr[base + i] = sorted[i];
}

// ---------------- GEMM1: h1b[N,64](bf16) = x[N,128] @ W1[128,64] ----------------
// 64 nodes/block; W staged once per 64 nodes; wave computes 16 nodes x 64 cols.
__global__ __launch_bounds__(256) void gemm1_kernel(const float* __restrict__ x,
                                                    const float* __restrict__ W,
                                                    ushort* __restrict__ h, int n) {
    __shared__ float Wl[F_IN * F_HID];   // 32 KB  [k][col]
    __shared__ float Xl[64 * F_IN];      // 32 KB  [row][k]
    int tid = threadIdx.x;
    int node0 = blockIdx.x * 64;
    // stage W (2048 float4s)
    for (int i4 = tid; i4 < 2048; i4 += 256)
        ((float4*)Wl)[i4] = ((const float4*)W)[i4];
    // stage X rows (2048 float4s, 32 float4 per row)
    for (int i4 = tid; i4 < 2048; i4 += 256) {
        int row  = i4 >> 5;
        int node = node0 + row;
        float4 v = make_float4(0.f, 0.f, 0.f, 0.f);
        if (node < n) v = *(const float4*)&x[(size_t)node * F_IN + ((i4 & 31) << 2)];
        ((float4*)Xl)[i4] = v;
    }
    __syncthreads();
    int wv    = tid >> 6;        // wave 0..3
    int col   = tid & 63;
    int rbase = wv * 16;         // 16 nodes per wave
    float acc[16];
    #pragma unroll
    for (int r = 0; r < 16; ++r) acc[r] = 0.f;
    for (int k0 = 0; k0 < F_IN; k0 += 4) {
        float w0 = Wl[(k0 + 0) * F_HID + col];
        float w1 = Wl[(k0 + 1) * F_HID + col];
        float w2 = Wl[(k0 + 2) * F_HID + col];
        float w3 = Wl[(k0 + 3) * F_HID + col];
        #pragma unroll
        for (int r = 0; r < 16; ++r) {
            float4 xv = *(const float4*)&Xl[(rbase + r) * F_IN + k0];
            acc[r] += xv.x * w0 + xv.y * w1 + xv.z * w2 + xv.w * w3;
        }
    }
    #pragma unroll
    for (int r = 0; r < 16; ++r) {
        int node = node0 + rbase + r;
        if (node < n) h[(size_t)node * F_HID + col] = f2bf(acc[r]);
    }
}

// ---------------- layer-1 gather + combine + ReLU (bf16 rows, 8 edges/iter) -------
__global__ void agg1_kernel(const int* __restrict__ rowstart, const int* __restrict__ csr,
                            const float* __restrict__ dinv, const ushort* __restrict__ h,
                            const float* __restrict__ b, ushort* __restrict__ out, int n) {
    int node = blockIdx.x * 4 + (threadIdx.x >> 6);
    int lane = threadIdx.x & 63;
    if (node >= n) return;
    int slot = lane >> 3;        // 0..7
    int c    = lane & 7;         // chunk -> features c*8 .. c*8+7
    int beg = rowstart[node], end = rowstart[node + 1];
    float acc[8] = {0.f,0.f,0.f,0.f,0.f,0.f,0.f,0.f};
    for (int base = beg; base < end; base += 64) {
        int idx = base + lane;
        int   sid = 0; float wgt = 0.f;
        if (idx < end) { sid = csr[idx]; wgt = dinv[sid]; }
        int cnt   = min(64, end - base);
        int iters = (cnt + 7) >> 3;
        for (int j = 0; j < iters; ++j) {
            int   sl = j * 8 + slot;
            int   s  = __shfl(sid, sl);
            float ww = __shfl(wgt, sl);
            uint4 hv = *(const uint4*)&h[(size_t)s * F_HID + (c << 3)];
            acc[0] += bf_lo(hv.x) * ww; acc[1] += bf_hi(hv.x) * ww;
            acc[2] += bf_lo(hv.y) * ww; acc[3] += bf_hi(hv.y) * ww;
            acc[4] += bf_lo(hv.z) * ww; acc[5] += bf_hi(hv.z) * ww;
            acc[6] += bf_lo(hv.w) * ww; acc[7] += bf_hi(hv.w) * ww;
        }
    }
    #pragma unroll
    for (int m = 8; m < 64; m <<= 1) {
        #pragma unroll
        for (int k = 0; k < 8; ++k) acc[k] += __shfl_xor(acc[k], m);
    }
    if (slot == 0) {
        float di = dinv[node];
        uint4 hs = *(const uint4*)&h[(size_t)node * F_HID + (c << 3)];
        float self[8] = { bf_lo(hs.x), bf_hi(hs.x), bf_lo(hs.y), bf_hi(hs.y),
                          bf_lo(hs.z), bf_hi(hs.z), bf_lo(hs.w), bf_hi(hs.w) };
        float4 b0 = *(const float4*)&b[c << 3];
        float4 b1v = *(const float4*)&b[(c << 3) + 4];
        float bb[8] = { b0.x, b0.y, b0.z, b0.w, b1v.x, b1v.y, b1v.z, b1v.w };
        ushort o[8];
        #pragma unroll
        for (int k = 0; k < 8; ++k) {
            float v = fmaxf(acc[k] * di + self[k] * di * di + bb[k], 0.f);
            o[k] = f2bf(v);
        }
        uint4 pk;
        pk.x = (uint)o[0] | ((uint)o[1] << 16);
        pk.y = (uint)o[2] | ((uint)o[3] << 16);
        pk.z = (uint)o[4] | ((uint)o[5] << 16);
        pk.w = (uint)o[6] | ((uint)o[7] << 16);
        *(uint4*)&out[(size_t)node * F_HID + (c << 3)] = pk;
    }
}

// ---------------- GEMM2: h2b[N,40](bf16) = out1b[N,64](bf16) @ W2[64,40] ----------
__global__ void gemm2_kernel(const ushort* __restrict__ a, const float* __restrict__ W,
                             ushort* __restrict__ h, int n) {
    __shared__ float Wl[F_HID * F_OUT];
    int tid = threadIdx.x;
    for (int i = tid; i < F_HID * F_OUT; i += 256) Wl[i] = W[i];
    __syncthreads();
    long long idx = (long long)blockIdx.x * 256 + tid;
    if (idx >= (long long)n * F_OUT) return;
    int node = (int)(idx / F_OUT);
    int col  = (int)(idx - (long long)node * F_OUT);
    const uint* arow = (const uint*)(a + (size_t)node * F_HID);
    float acc = 0.0f;
    #pragma unroll 8
    for (int k = 0; k < F_HID / 2; ++k) {
        uint u = arow[k];
        acc += bf_lo(u) * Wl[(2 * k) * F_OUT + col] + bf_hi(u) * Wl[(2 * k + 1) * F_OUT + col];
    }
    h[idx] = f2bf(acc);
}

// ---------------- layer-2 gather + combine + log_softmax (bf16 rows) --------------
__global__ void agg2_kernel(const int* __restrict__ rowstart, const int* __restrict__ csr,
                            const float* __restrict__ dinv, const ushort* __restrict__ h,
                            const float* __restrict__ b, float* __restrict__ out, int n) {
    int node = blockIdx.x * 4 + (threadIdx.x >> 6);
    int lane = threadIdx.x & 63;
    if (node >= n) return;
    int slot = lane / 10;            // 0..6 (lanes 60..63 idle slot)
    int c    = lane - slot * 10;     // chunk -> features c*4..c*4+3
    int beg = rowstart[node], end = rowstart[node + 1];
    float acc[4] = {0.f, 0.f, 0.f, 0.f};
    for (int base = beg; base < end; base += 60) {
        int idx = base + lane;
        int   sid = 0; float wgt = 0.f;
        if (lane < 60 && idx < end) { sid = csr[idx]; wgt = dinv[sid]; }
        int cnt   = min(60, end - base);
        int iters = (cnt + 5) / 6;
        for (int j = 0; j < iters; ++j) {
            int   sl = (slot < 6) ? (j * 6 + slot) : 60;
            int   s  = __shfl(sid, sl);
            float ww = __shfl(wgt, sl);
            uint2 hv = *(const uint2*)&h[(size_t)s * F_OUT + (c << 2)];
            acc[0] += bf_lo(hv.x) * ww; acc[1] += bf_hi(hv.x) * ww;
            acc[2] += bf_lo(hv.y) * ww; acc[3] += bf_hi(hv.y) * ww;
        }
    }
    float r[4] = { acc[0], acc[1], acc[2], acc[3] };
    #pragma unroll
    for (int k = 1; k < 6; ++k) {
        int sl = lane + k * 10;
        r[0] += __shfl(acc[0], sl); r[1] += __shfl(acc[1], sl);
        r[2] += __shfl(acc[2], sl); r[3] += __shfl(acc[3], sl);
    }
    float val[4] = {0.f, 0.f, 0.f, 0.f};
    float m = -INFINITY;
    if (lane < 10) {
        float di = dinv[node];
        uint2 hs = *(const uint2*)&h[(size_t)node * F_OUT + (c << 2)];
        float self[4] = { bf_lo(hs.x), bf_hi(hs.x), bf_lo(hs.y), bf_hi(hs.y) };
        float4 bb = *(const float4*)&b[c << 2];
        float bbv[4] = { bb.x, bb.y, bb.z, bb.w };
        #pragma unroll
        for (int k = 0; k < 4; ++k) {
            val[k] = r[k] * di + self[k] * di * di + bbv[k];
            m = fmaxf(m, val[k]);
        }
    }
    #pragma unroll
    for (int off = 1; off < 16; off <<= 1) m = fmaxf(m, __shfl_xor(m, off));
    float p = 0.f;
    if (lane < 10)
        p = __expf(val[0] - m) + __expf(val[1] - m) + __expf(val[2] - m) + __expf(val[3] - m);
    #pragma unroll
    for (int off = 1; off < 16; off <<= 1) p += __shfl_xor(p, off);
    float lse = m + __logf(p);
    if (lane < 10) {
        float4 o;
        o.x = val[0] - lse; o.y = val[1] - lse; o.z = val[2] - lse; o.w = val[3] - lse;
        *(float4*)&out[(size_t)node * F_OUT + (c << 2)] = o;
    }
}

extern "C" void kernel_launch(void* const* d_in, const int* in_sizes, int n_in,
                              void* d_out, int out_size, void* d_ws, size_t ws_size,
                              hipStream_t stream) {
    const float* x  = (const float*)d_in[0];
    const int*   ei = (const int*)d_in[1];
    const float* W1 = (const float*)d_in[2];
    const float* b1 = (const float*)d_in[3];
    const float* W2 = (const float*)d_in[4];
    const float* b2 = (const float*)d_in[5];
    const int* src = ei;
    const int* dst = ei + N_EDGES;

    // workspace layout (all chunks 16B-aligned)
    char* p = (char*)d_ws;
    int*    bcount   = (int*)p;     p += (size_t)(NBINS + 4) * 4;
    int*    bstart   = (int*)p;     p += (size_t)(NBINS + 4) * 4;
    int*    bcursor  = (int*)p;     p += (size_t)(NBINS + 4) * 4;
    int*    bins     = (int*)p;     p += (size_t)N_EDGES * 4;
    int*    csr_src  = (int*)p;     p += (size_t)N_EDGES * 4;
    int*    rowstart = (int*)p;     p += (size_t)(N_NODES + 4) * 4;
    float*  dinv     = (float*)p;   p += (size_t)N_NODES * 4;
    ushort* h1b      = (ushort*)p;  p += (size_t)N_NODES * F_HID * 2;
    ushort* out1b    = (ushort*)p;  p += (size_t)N_NODES * F_HID * 2;
    ushort* h2b      = (ushort*)p;  p += (size_t)N_NODES * F_OUT * 2;
    float*  out      = (float*)d_out;

    hipMemsetAsync(bcount, 0, (size_t)NBINS * 4, stream);

    bincount_kernel<<<FILL_BLOCKS, 256, 0, stream>>>(dst, bcount, N_EDGES);
    binscan_kernel <<<1, 256, 0, stream>>>(bcount, bstart, bcursor, rowstart);
    binfill_kernel <<<FILL_BLOCKS, 256, 0, stream>>>(src, dst, bcursor, bins, N_EDGES);
    binsort_kernel <<<NBINS, 512, 0, stream>>>(bstart, bins, csr_src, rowstart, dinv);
    gemm1_kernel<<<(N_NODES + 63) / 64, 256, 0, stream>>>(x, W1, h1b, N_NODES);
    agg1_kernel <<<(N_NODES + 3) / 4, 256, 0, stream>>>(rowstart, csr_src, dinv, h1b, b1,
                                                        out1b, N_NODES);
    gemm2_kernel<<<((N_NODES * F_OUT) + 255) / 256, 256, 0, stream>>>(out1b, W2, h2b, N_NODES);
    agg2_kernel <<<(N_NODES + 3) / 4, 256, 0, stream>>>(rowstart, csr_src, dinv, h2b, b2,
                                                        out, N_NODES);
}

// Round 7
// 302.320 us; speedup vs baseline: 3.1907x; 1.1322x over previous
//
#include <hip/hip_runtime.h>
#include <math.h>

#define N_NODES 100000
#define N_EDGES 1600000
#define F_IN    128
#define F_HID   64
#define F_OUT   40

#define BIN_SHIFT 9
#define NBINS     196          // ceil(100000 / 512)
#define MAX_BIN   10240
#define FILL_BLOCKS 256

typedef unsigned int  uint;
typedef unsigned short ushort;
typedef __attribute__((ext_vector_type(8))) short bf16x8;   // 4 VGPRs
typedef __attribute__((ext_vector_type(4))) float f32x4;    // MFMA acc

__device__ __forceinline__ unsigned short f2bf(float f) {      // RNE, finite inputs
    uint u = __float_as_uint(f);
    u = (u + 0x7FFF + ((u >> 16) & 1)) >> 16;
    return (unsigned short)u;
}
__device__ __forceinline__ uint pack2bf(float a, float b) {
    return (uint)f2bf(a) | ((uint)f2bf(b) << 16);
}
__device__ __forceinline__ float bf_lo(uint u) { return __uint_as_float(u << 16); }
__device__ __forceinline__ float bf_hi(uint u) { return __uint_as_float(u & 0xFFFF0000u); }

// ---------------- pass 0: global bin counts ----------------
__global__ void bincount_kernel(const int* __restrict__ dst, int* __restrict__ bcount, int E) {
    __shared__ int lc[NBINS];
    int tid = threadIdx.x;
    for (int i = tid; i < NBINS; i += 256) lc[i] = 0;
    __syncthreads();
    int chunk = (E + gridDim.x - 1) / gridDim.x;
    int beg = blockIdx.x * chunk, end = min(E, beg + chunk);
    for (int e = beg + tid; e < end; e += 256)
        atomicAdd(&lc[dst[e] >> BIN_SHIFT], 1);
    __syncthreads();
    for (int i = tid; i < NBINS; i += 256)
        if (lc[i]) atomicAdd(&bcount[i], lc[i]);
}

// ---------------- pass 1: scan bin counts ----------------
__global__ void binscan_kernel(const int* __restrict__ bcount, int* __restrict__ bstart,
                               int* __restrict__ bcursor, int* __restrict__ rowstart) {
    __shared__ int tmp[256];
    int t = threadIdx.x;
    int v = (t < NBINS) ? bcount[t] : 0;
    tmp[t] = v;
    __syncthreads();
    for (int off = 1; off < 256; off <<= 1) {
        int u = (t >= off) ? tmp[t - off] : 0;
        __syncthreads();
        tmp[t] += u;
        __syncthreads();
    }
    if (t < NBINS) { int e = tmp[t] - v; bstart[t] = e; bcursor[t] = e; }
    if (t == 0) { bstart[NBINS] = N_EDGES; rowstart[N_NODES] = N_EDGES; }
}

// ---------------- pass 2: binned scatter of packed (src | ldst<<17) ----------------
__global__ void binfill_kernel(const int* __restrict__ src, const int* __restrict__ dst,
                               int* __restrict__ bcursor, int* __restrict__ bins, int E) {
    __shared__ int lcount[NBINS];
    __shared__ int gbase[NBINS];
    int tid = threadIdx.x;
    for (int i = tid; i < NBINS; i += 256) lcount[i] = 0;
    __syncthreads();
    int chunk = (E + gridDim.x - 1) / gridDim.x;
    int beg = blockIdx.x * chunk, end = min(E, beg + chunk);
    for (int e = beg + tid; e < end; e += 256)
        atomicAdd(&lcount[dst[e] >> BIN_SHIFT], 1);
    __syncthreads();
    for (int i = tid; i < NBINS; i += 256) {
        gbase[i] = lcount[i] ? atomicAdd(&bcursor[i], lcount[i]) : 0;
        lcount[i] = 0;
    }
    __syncthreads();
    for (int e = beg + tid; e < end; e += 256) {
        int d = dst[e];
        int b = d >> BIN_SHIFT;
        int p = atomicAdd(&lcount[b], 1);
        bins[gbase[b] + p] = src[e] | ((d & 511) << 17);
    }
}

// ---------------- pass 3: per-bin counting sort ----------------
__global__ void binsort_kernel(const int* __restrict__ bstart, const int* __restrict__ bins,
                               int* __restrict__ csr, int* __restrict__ rowstart,
                               float* __restrict__ dinv) {
    __shared__ int hist[512];
    __shared__ int scan[512];
    __shared__ int cur[512];
    __shared__ int sorted[MAX_BIN];
    int b = blockIdx.x, t = threadIdx.x;
    int base = bstart[b], cnt = bstart[b + 1] - base;
    hist[t] = 0;
    __syncthreads();
    for (int i = t; i < cnt; i += 512)
        atomicAdd(&hist[(unsigned)bins[base + i] >> 17], 1);
    __syncthreads();
    int v = hist[t];
    scan[t] = v;
    __syncthreads();
    for (int off = 1; off < 512; off <<= 1) {
        int u = (t >= off) ? scan[t - off] : 0;
        __syncthreads();
        scan[t] += u;
        __syncthreads();
    }
    int excl = scan[t] - v;
    cur[t] = excl;
    int node = (b << BIN_SHIFT) + t;
    if (node < N_NODES) {
        rowstart[node] = base + excl;
        dinv[node] = rsqrtf((float)v + 1.0f);
    }
    __syncthreads();
    for (int i = t; i < cnt; i += 512) {
        int p   = bins[base + i];
        int pos = atomicAdd(&cur[(unsigned)p >> 17], 1);
        sorted[pos] = p & 0x1FFFF;
    }
    __syncthreads();
    for (int i = t; i < cnt; i += 512)
        csr[base + i] = sorted[i];
}

// ---------------- W1 transpose to bf16: Wt[n(64)][k(128)] ----------------
__global__ void wtrans_kernel(const float* __restrict__ W, uint* __restrict__ Wt) {
    int tid = threadIdx.x;
    for (int i = tid; i < 4096; i += 256) {       // uint index: c*64 + kpair
        int c  = i >> 6;
        int kp = i & 63;
        Wt[i] = pack2bf(W[(2 * kp) * F_HID + c], W[(2 * kp + 1) * F_HID + c]);
    }
}

// ---------------- GEMM1 (MFMA): h1b[N,64](bf16) = bf16(x) @ bf16(W1) ----------------
// 64 nodes/block, 4 waves; wave w -> rows w*16..+15, all 64 cols (4 n-tiles).
#define XPITCH 68   // uints per row (64 + 4 pad) to spread b128 bank groups
__global__ __launch_bounds__(256) void gemm1_kernel(const float* __restrict__ x,
                                                    const uint* __restrict__ Wt,
                                                    ushort* __restrict__ h, int n) {
    __shared__ __align__(16) uint Xu[64 * XPITCH];   // 17.4 KB bf16 x-rows
    __shared__ __align__(16) uint Wu[64 * XPITCH];   // 17.4 KB bf16 Wt rows
    int tid = threadIdx.x;
    int node0 = blockIdx.x * 64;

    // stage Wt: thread -> col c = tid>>2, quarter qq = tid&3 (16 uints)
    {
        int c = tid >> 2, qq = tid & 3;
        const uint4* gsrc = (const uint4*)&Wt[c * 64 + qq * 16];
        uint4* ldst = (uint4*)&Wu[c * XPITCH + qq * 16];
        #pragma unroll
        for (int j = 0; j < 4; ++j) ldst[j] = gsrc[j];
    }
    // stage X rows with fp32->bf16 convert: thread -> row = tid>>2, quarter = tid&3
    {
        int row = tid >> 2, qq = tid & 3;
        int node = node0 + row;
        uint4* ldst = (uint4*)&Xu[row * XPITCH + qq * 16];
        if (node < n) {
            const float4* gsrc = (const float4*)&x[(size_t)node * F_IN + qq * 32];
            #pragma unroll
            for (int j = 0; j < 4; ++j) {
                float4 a = gsrc[2 * j], b = gsrc[2 * j + 1];
                uint4 o;
                o.x = pack2bf(a.x, a.y); o.y = pack2bf(a.z, a.w);
                o.z = pack2bf(b.x, b.y); o.w = pack2bf(b.z, b.w);
                ldst[j] = o;
            }
        } else {
            uint4 z = make_uint4(0, 0, 0, 0);
            #pragma unroll
            for (int j = 0; j < 4; ++j) ldst[j] = z;
        }
    }
    __syncthreads();

    int wv   = tid >> 6;        // wave 0..3
    int lane = tid & 63;
    int lrow = lane & 15;       // row/col-within-tile index
    int quad = lane >> 4;       // 0..3

    // hoist all B fragments (4 n-tiles x 4 k-steps) into registers
    bf16x8 bfrag[4][4];
    #pragma unroll
    for (int t = 0; t < 4; ++t)
        #pragma unroll
        for (int s = 0; s < 4; ++s)
            bfrag[t][s] = *(const bf16x8*)&Wu[(t * 16 + lrow) * XPITCH + s * 16 + quad * 4];

    f32x4 acc[4];
    #pragma unroll
    for (int t = 0; t < 4; ++t) acc[t] = (f32x4){0.f, 0.f, 0.f, 0.f};

    #pragma unroll
    for (int s = 0; s < 4; ++s) {
        bf16x8 afrag = *(const bf16x8*)&Xu[(wv * 16 + lrow) * XPITCH + s * 16 + quad * 4];
        #pragma unroll
        for (int t = 0; t < 4; ++t)
            acc[t] = __builtin_amdgcn_mfma_f32_16x16x32_bf16(afrag, bfrag[t][s], acc[t], 0, 0, 0);
    }

    // epilogue: C/D layout col=lane&15, row=quad*4+i
    #pragma unroll
    for (int t = 0; t < 4; ++t) {
        #pragma unroll
        for (int i = 0; i < 4; ++i) {
            int node = node0 + wv * 16 + quad * 4 + i;
            if (node < n) h[(size_t)node * F_HID + t * 16 + lrow] = f2bf(acc[t][i]);
        }
    }
}

// ---------------- layer-1 gather + combine + ReLU (bf16 rows, 8 edges/iter) -------
__global__ void agg1_kernel(const int* __restrict__ rowstart, const int* __restrict__ csr,
                            const float* __restrict__ dinv, const ushort* __restrict__ h,
                            const float* __restrict__ b, ushort* __restrict__ out, int n) {
    int node = blockIdx.x * 4 + (threadIdx.x >> 6);
    int lane = threadIdx.x & 63;
    if (node >= n) return;
    int slot = lane >> 3;        // 0..7
    int c    = lane & 7;         // chunk -> features c*8 .. c*8+7
    int beg = rowstart[node], end = rowstart[node + 1];
    float acc[8] = {0.f,0.f,0.f,0.f,0.f,0.f,0.f,0.f};
    for (int base = beg; base < end; base += 64) {
        int idx = base + lane;
        int   sid = 0; float wgt = 0.f;
        if (idx < end) { sid = csr[idx]; wgt = dinv[sid]; }
        int cnt   = min(64, end - base);
        int iters = (cnt + 7) >> 3;
        for (int j = 0; j < iters; ++j) {
            int   sl = j * 8 + slot;
            int   s  = __shfl(sid, sl);
            float ww = __shfl(wgt, sl);
            uint4 hv = *(const uint4*)&h[(size_t)s * F_HID + (c << 3)];
            acc[0] += bf_lo(hv.x) * ww; acc[1] += bf_hi(hv.x) * ww;
            acc[2] += bf_lo(hv.y) * ww; acc[3] += bf_hi(hv.y) * ww;
            acc[4] += bf_lo(hv.z) * ww; acc[5] += bf_hi(hv.z) * ww;
            acc[6] += bf_lo(hv.w) * ww; acc[7] += bf_hi(hv.w) * ww;
        }
    }
    #pragma unroll
    for (int m = 8; m < 64; m <<= 1) {
        #pragma unroll
        for (int k = 0; k < 8; ++k) acc[k] += __shfl_xor(acc[k], m);
    }
    if (slot == 0) {
        float di = dinv[node];
        uint4 hs = *(const uint4*)&h[(size_t)node * F_HID + (c << 3)];
        float self[8] = { bf_lo(hs.x), bf_hi(hs.x), bf_lo(hs.y), bf_hi(hs.y),
                          bf_lo(hs.z), bf_hi(hs.z), bf_lo(hs.w), bf_hi(hs.w) };
        float4 b0 = *(const float4*)&b[c << 3];
        float4 b1v = *(const float4*)&b[(c << 3) + 4];
        float bb[8] = { b0.x, b0.y, b0.z, b0.w, b1v.x, b1v.y, b1v.z, b1v.w };
        ushort o[8];
        #pragma unroll
        for (int k = 0; k < 8; ++k) {
            float v = fmaxf(acc[k] * di + self[k] * di * di + bb[k], 0.f);
            o[k] = f2bf(v);
        }
        uint4 pk;
        pk.x = (uint)o[0] | ((uint)o[1] << 16);
        pk.y = (uint)o[2] | ((uint)o[3] << 16);
        pk.z = (uint)o[4] | ((uint)o[5] << 16);
        pk.w = (uint)o[6] | ((uint)o[7] << 16);
        *(uint4*)&out[(size_t)node * F_HID + (c << 3)] = pk;
    }
}

// ---------------- GEMM2: h2b[N,40](bf16) = out1b[N,64](bf16) @ W2[64,40] ----------
__global__ void gemm2_kernel(const ushort* __restrict__ a, const float* __restrict__ W,
                             ushort* __restrict__ h, int n) {
    __shared__ float Wl[F_HID * F_OUT];
    int tid = threadIdx.x;
    for (int i = tid; i < F_HID * F_OUT; i += 256) Wl[i] = W[i];
    __syncthreads();
    long long idx = (long long)blockIdx.x * 256 + tid;
    if (idx >= (long long)n * F_OUT) return;
    int node = (int)(idx / F_OUT);
    int col  = (int)(idx - (long long)node * F_OUT);
    const uint* arow = (const uint*)(a + (size_t)node * F_HID);
    float acc = 0.0f;
    #pragma unroll 8
    for (int k = 0; k < F_HID / 2; ++k) {
        uint u = arow[k];
        acc += bf_lo(u) * Wl[(2 * k) * F_OUT + col] + bf_hi(u) * Wl[(2 * k + 1) * F_OUT + col];
    }
    h[idx] = f2bf(acc);
}

// ---------------- layer-2 gather + combine + log_softmax (bf16 rows) --------------
__global__ void agg2_kernel(const int* __restrict__ rowstart, const int* __restrict__ csr,
                            const float* __restrict__ dinv, const ushort* __restrict__ h,
                            const float* __restrict__ b, float* __restrict__ out, int n) {
    int node = blockIdx.x * 4 + (threadIdx.x >> 6);
    int lane = threadIdx.x & 63;
    if (node >= n) return;
    int slot = lane / 10;            // 0..6 (lanes 60..63 idle slot)
    int c    = lane - slot * 10;     // chunk -> features c*4..c*4+3
    int beg = rowstart[node], end = rowstart[node + 1];
    float acc[4] = {0.f, 0.f, 0.f, 0.f};
    for (int base = beg; base < end; base += 60) {
        int idx = base + lane;
        int   sid = 0; float wgt = 0.f;
        if (lane < 60 && idx < end) { sid = csr[idx]; wgt = dinv[sid]; }
        int cnt   = min(60, end - base);
        int iters = (cnt + 5) / 6;
        for (int j = 0; j < iters; ++j) {
            int   sl = (slot < 6) ? (j * 6 + slot) : 60;
            int   s  = __shfl(sid, sl);
            float ww = __shfl(wgt, sl);
            uint2 hv = *(const uint2*)&h[(size_t)s * F_OUT + (c << 2)];
            acc[0] += bf_lo(hv.x) * ww; acc[1] += bf_hi(hv.x) * ww;
            acc[2] += bf_lo(hv.y) * ww; acc[3] += bf_hi(hv.y) * ww;
        }
    }
    float r[4] = { acc[0], acc[1], acc[2], acc[3] };
    #pragma unroll
    for (int k = 1; k < 6; ++k) {
        int sl = lane + k * 10;
        r[0] += __shfl(acc[0], sl); r[1] += __shfl(acc[1], sl);
        r[2] += __shfl(acc[2], sl); r[3] += __shfl(acc[3], sl);
    }
    float val[4] = {0.f, 0.f, 0.f, 0.f};
    float m = -INFINITY;
    if (lane < 10) {
        float di = dinv[node];
        uint2 hs = *(const uint2*)&h[(size_t)node * F_OUT + (c << 2)];
        float self[4] = { bf_lo(hs.x), bf_hi(hs.x), bf_lo(hs.y), bf_hi(hs.y) };
        float4 bb = *(const float4*)&b[c << 2];
        float bbv[4] = { bb.x, bb.y, bb.z, bb.w };
        #pragma unroll
        for (int k = 0; k < 4; ++k) {
            val[k] = r[k] * di + self[k] * di * di + bbv[k];
            m = fmaxf(m, val[k]);
        }
    }
    #pragma unroll
    for (int off = 1; off < 16; off <<= 1) m = fmaxf(m, __shfl_xor(m, off));
    float p = 0.f;
    if (lane < 10)
        p = __expf(val[0] - m) + __expf(val[1] - m) + __expf(val[2] - m) + __expf(val[3] - m);
    #pragma unroll
    for (int off = 1; off < 16; off <<= 1) p += __shfl_xor(p, off);
    float lse = m + __logf(p);
    if (lane < 10) {
        float4 o;
        o.x = val[0] - lse; o.y = val[1] - lse; o.z = val[2] - lse; o.w = val[3] - lse;
        *(float4*)&out[(size_t)node * F_OUT + (c << 2)] = o;
    }
}

extern "C" void kernel_launch(void* const* d_in, const int* in_sizes, int n_in,
                              void* d_out, int out_size, void* d_ws, size_t ws_size,
                              hipStream_t stream) {
    const float* x  = (const float*)d_in[0];
    const int*   ei = (const int*)d_in[1];
    const float* W1 = (const float*)d_in[2];
    const float* b1 = (const float*)d_in[3];
    const float* W2 = (const float*)d_in[4];
    const float* b2 = (const float*)d_in[5];
    const int* src = ei;
    const int* dst = ei + N_EDGES;

    // workspace layout (all chunks 16B-aligned)
    char* p = (char*)d_ws;
    int*    bcount   = (int*)p;     p += (size_t)(NBINS + 4) * 4;
    int*    bstart   = (int*)p;     p += (size_t)(NBINS + 4) * 4;
    int*    bcursor  = (int*)p;     p += (size_t)(NBINS + 4) * 4;
    int*    bins     = (int*)p;     p += (size_t)N_EDGES * 4;
    int*    csr_src  = (int*)p;     p += (size_t)N_EDGES * 4;
    int*    rowstart = (int*)p;     p += (size_t)(N_NODES + 4) * 4;
    float*  dinv     = (float*)p;   p += (size_t)N_NODES * 4;
    uint*   Wtb      = (uint*)p;    p += (size_t)4096 * 4;       // W1^T bf16 [64][128]
    ushort* h1b      = (ushort*)p;  p += (size_t)N_NODES * F_HID * 2;
    ushort* out1b    = (ushort*)p;  p += (size_t)N_NODES * F_HID * 2;
    ushort* h2b      = (ushort*)p;  p += (size_t)N_NODES * F_OUT * 2;
    float*  out      = (float*)d_out;

    hipMemsetAsync(bcount, 0, (size_t)NBINS * 4, stream);

    bincount_kernel<<<FILL_BLOCKS, 256, 0, stream>>>(dst, bcount, N_EDGES);
    binscan_kernel <<<1, 256, 0, stream>>>(bcount, bstart, bcursor, rowstart);
    binfill_kernel <<<FILL_BLOCKS, 256, 0, stream>>>(src, dst, bcursor, bins, N_EDGES);
    binsort_kernel <<<NBINS, 512, 0, stream>>>(bstart, bins, csr_src, rowstart, dinv);
    wtrans_kernel<<<1, 256, 0, stream>>>(W1, Wtb);
    gemm1_kernel<<<(N_NODES + 63) / 64, 256, 0, stream>>>(x, Wtb, h1b, N_NODES);
    agg1_kernel <<<(N_NODES + 3) / 4, 256, 0, stream>>>(rowstart, csr_src, dinv, h1b, b1,
                                                        out1b, N_NODES);
    gemm2_kernel<<<((N_NODES * F_OUT) + 255) / 256, 256, 0, stream>>>(out1b, W2, h2b, N_NODES);
    agg2_kernel <<<(N_NODES + 3) / 4, 256, 0, stream>>>(rowstart, csr_src, dinv, h2b, b2,
                                                        out, N_NODES);
}

// Round 8
// 296.796 us; speedup vs baseline: 3.2501x; 1.0186x over previous
//
#include <hip/hip_runtime.h>
#include <math.h>

#define N_NODES 100000
#define N_EDGES 1600000
#define F_IN    128
#define F_HID   64
#define F_OUT   40

#define BIN_SHIFT 9
#define NBINS     196          // ceil(100000 / 512)
#define MAX_BIN   10240
#define FILL_BLOCKS 256

typedef unsigned int  uint;
typedef unsigned short ushort;
typedef __attribute__((ext_vector_type(8))) short bf16x8;   // 4 VGPRs
typedef __attribute__((ext_vector_type(4))) float f32x4;    // MFMA acc

__device__ __forceinline__ unsigned short f2bf(float f) {      // RNE, finite inputs
    uint u = __float_as_uint(f);
    u = (u + 0x7FFF + ((u >> 16) & 1)) >> 16;
    return (unsigned short)u;
}
__device__ __forceinline__ uint pack2bf(float a, float b) {
    return (uint)f2bf(a) | ((uint)f2bf(b) << 16);
}
__device__ __forceinline__ float bf_lo(uint u) { return __uint_as_float(u << 16); }
__device__ __forceinline__ float bf_hi(uint u) { return __uint_as_float(u & 0xFFFF0000u); }

// ---------------- pass 0: global bin counts ----------------
__global__ void bincount_kernel(const int* __restrict__ dst, int* __restrict__ bcount, int E) {
    __shared__ int lc[NBINS];
    int tid = threadIdx.x;
    for (int i = tid; i < NBINS; i += 256) lc[i] = 0;
    __syncthreads();
    int chunk = (E + gridDim.x - 1) / gridDim.x;
    int beg = blockIdx.x * chunk, end = min(E, beg + chunk);
    for (int e = beg + tid; e < end; e += 256)
        atomicAdd(&lc[dst[e] >> BIN_SHIFT], 1);
    __syncthreads();
    for (int i = tid; i < NBINS; i += 256)
        if (lc[i]) atomicAdd(&bcount[i], lc[i]);
}

// ---------------- pass 1: scan bin counts ----------------
__global__ void binscan_kernel(const int* __restrict__ bcount, int* __restrict__ bstart,
                               int* __restrict__ bcursor, int* __restrict__ rowstart) {
    __shared__ int tmp[256];
    int t = threadIdx.x;
    int v = (t < NBINS) ? bcount[t] : 0;
    tmp[t] = v;
    __syncthreads();
    for (int off = 1; off < 256; off <<= 1) {
        int u = (t >= off) ? tmp[t - off] : 0;
        __syncthreads();
        tmp[t] += u;
        __syncthreads();
    }
    if (t < NBINS) { int e = tmp[t] - v; bstart[t] = e; bcursor[t] = e; }
    if (t == 0) { bstart[NBINS] = N_EDGES; rowstart[N_NODES] = N_EDGES; }
}

// ---------------- pass 2: binned scatter of packed (src | ldst<<17) ----------------
__global__ void binfill_kernel(const int* __restrict__ src, const int* __restrict__ dst,
                               int* __restrict__ bcursor, int* __restrict__ bins, int E) {
    __shared__ int lcount[NBINS];
    __shared__ int gbase[NBINS];
    int tid = threadIdx.x;
    for (int i = tid; i < NBINS; i += 256) lcount[i] = 0;
    __syncthreads();
    int chunk = (E + gridDim.x - 1) / gridDim.x;
    int beg = blockIdx.x * chunk, end = min(E, beg + chunk);
    for (int e = beg + tid; e < end; e += 256)
        atomicAdd(&lcount[dst[e] >> BIN_SHIFT], 1);
    __syncthreads();
    for (int i = tid; i < NBINS; i += 256) {
        gbase[i] = lcount[i] ? atomicAdd(&bcursor[i], lcount[i]) : 0;
        lcount[i] = 0;
    }
    __syncthreads();
    for (int e = beg + tid; e < end; e += 256) {
        int d = dst[e];
        int b = d >> BIN_SHIFT;
        int p = atomicAdd(&lcount[b], 1);
        bins[gbase[b] + p] = src[e] | ((d & 511) << 17);
    }
}

// ---------------- pass 3: per-bin counting sort ----------------
__global__ void binsort_kernel(const int* __restrict__ bstart, const int* __restrict__ bins,
                               int* __restrict__ csr, int* __restrict__ rowstart,
                               float* __restrict__ dinv) {
    __shared__ int hist[512];
    __shared__ int scan[512];
    __shared__ int cur[512];
    __shared__ int sorted[MAX_BIN];
    int b = blockIdx.x, t = threadIdx.x;
    int base = bstart[b], cnt = bstart[b + 1] - base;
    hist[t] = 0;
    __syncthreads();
    for (int i = t; i < cnt; i += 512)
        atomicAdd(&hist[(unsigned)bins[base + i] >> 17], 1);
    __syncthreads();
    int v = hist[t];
    scan[t] = v;
    __syncthreads();
    for (int off = 1; off < 512; off <<= 1) {
        int u = (t >= off) ? scan[t - off] : 0;
        __syncthreads();
        scan[t] += u;
        __syncthreads();
    }
    int excl = scan[t] - v;
    cur[t] = excl;
    int node = (b << BIN_SHIFT) + t;
    if (node < N_NODES) {
        rowstart[node] = base + excl;
        dinv[node] = rsqrtf((float)v + 1.0f);
    }
    __syncthreads();
    for (int i = t; i < cnt; i += 512) {
        int p   = bins[base + i];
        int pos = atomicAdd(&cur[(unsigned)p >> 17], 1);
        sorted[pos] = p & 0x1FFFF;
    }
    __syncthreads();
    for (int i = t; i < cnt; i += 512)
        csr[base + i] = sorted[i];
}

// ---------------- W1 transpose to bf16: Wt[n(64)][k(128)] ----------------
__global__ void wtrans_kernel(const float* __restrict__ W, uint* __restrict__ Wt) {
    int tid = threadIdx.x;
    for (int i = tid; i < 4096; i += 256) {       // uint index: c*64 + kpair
        int c  = i >> 6;
        int kp = i & 63;
        Wt[i] = pack2bf(W[(2 * kp) * F_HID + c], W[(2 * kp + 1) * F_HID + c]);
    }
}

// ---------------- GEMM1 (MFMA): h1b[N,64](bf16) = bf16(x) @ bf16(W1) ----------------
#define XPITCH 68   // uints per row (64 + 4 pad)
__global__ __launch_bounds__(256) void gemm1_kernel(const float* __restrict__ x,
                                                    const uint* __restrict__ Wt,
                                                    ushort* __restrict__ h, int n) {
    __shared__ __align__(16) uint Xu[64 * XPITCH];
    __shared__ __align__(16) uint Wu[64 * XPITCH];
    int tid = threadIdx.x;
    int node0 = blockIdx.x * 64;

    {
        int c = tid >> 2, qq = tid & 3;
        const uint4* gsrc = (const uint4*)&Wt[c * 64 + qq * 16];
        uint4* ldst = (uint4*)&Wu[c * XPITCH + qq * 16];
        #pragma unroll
        for (int j = 0; j < 4; ++j) ldst[j] = gsrc[j];
    }
    {
        int row = tid >> 2, qq = tid & 3;
        int node = node0 + row;
        uint4* ldst = (uint4*)&Xu[row * XPITCH + qq * 16];
        if (node < n) {
            const float4* gsrc = (const float4*)&x[(size_t)node * F_IN + qq * 32];
            #pragma unroll
            for (int j = 0; j < 4; ++j) {
                float4 a = gsrc[2 * j], b = gsrc[2 * j + 1];
                uint4 o;
                o.x = pack2bf(a.x, a.y); o.y = pack2bf(a.z, a.w);
                o.z = pack2bf(b.x, b.y); o.w = pack2bf(b.z, b.w);
                ldst[j] = o;
            }
        } else {
            uint4 z = make_uint4(0, 0, 0, 0);
            #pragma unroll
            for (int j = 0; j < 4; ++j) ldst[j] = z;
        }
    }
    __syncthreads();

    int wv   = tid >> 6;
    int lane = tid & 63;
    int lrow = lane & 15;
    int quad = lane >> 4;

    bf16x8 bfrag[4][4];
    #pragma unroll
    for (int t = 0; t < 4; ++t)
        #pragma unroll
        for (int s = 0; s < 4; ++s)
            bfrag[t][s] = *(const bf16x8*)&Wu[(t * 16 + lrow) * XPITCH + s * 16 + quad * 4];

    f32x4 acc[4];
    #pragma unroll
    for (int t = 0; t < 4; ++t) acc[t] = (f32x4){0.f, 0.f, 0.f, 0.f};

    #pragma unroll
    for (int s = 0; s < 4; ++s) {
        bf16x8 afrag = *(const bf16x8*)&Xu[(wv * 16 + lrow) * XPITCH + s * 16 + quad * 4];
        #pragma unroll
        for (int t = 0; t < 4; ++t)
            acc[t] = __builtin_amdgcn_mfma_f32_16x16x32_bf16(afrag, bfrag[t][s], acc[t], 0, 0, 0);
    }

    #pragma unroll
    for (int t = 0; t < 4; ++t) {
        #pragma unroll
        for (int i = 0; i < 4; ++i) {
            int node = node0 + wv * 16 + quad * 4 + i;
            if (node < n) h[(size_t)node * F_HID + t * 16 + lrow] = f2bf(acc[t][i]);
        }
    }
}

// ---------------- layer-1 gather + combine + ReLU (pipelined, 16 edges in flight) --
__global__ void agg1_kernel(const int* __restrict__ rowstart, const int* __restrict__ csr,
                            const float* __restrict__ dinv, const ushort* __restrict__ h,
                            const float* __restrict__ b, ushort* __restrict__ out, int n) {
    int node = blockIdx.x * 4 + (threadIdx.x >> 6);
    int lane = threadIdx.x & 63;
    if (node >= n) return;
    int slot = lane >> 3;        // 0..7
    int c    = lane & 7;         // chunk -> features c*8 .. c*8+7
    int beg = rowstart[node], end = rowstart[node + 1];
    float acc[8] = {0.f,0.f,0.f,0.f,0.f,0.f,0.f,0.f};
    for (int base = beg; base < end; base += 64) {
        int idx = base + lane;
        int   sid = 0; float wgt = 0.f;
        if (idx < end) { sid = csr[idx]; wgt = dinv[sid]; }
        int cnt    = min(64, end - base);
        int groups = (cnt + 7) >> 3;
        int g = 0;
        for (; g + 2 <= groups; g += 2) {
            int   sA = __shfl(sid, g * 8 + slot);
            float wA = __shfl(wgt, g * 8 + slot);
            int   sB = __shfl(sid, g * 8 + 8 + slot);
            float wB = __shfl(wgt, g * 8 + 8 + slot);
            uint4 hA = *(const uint4*)&h[(size_t)sA * F_HID + (c << 3)];
            uint4 hB = *(const uint4*)&h[(size_t)sB * F_HID + (c << 3)];
            acc[0] += bf_lo(hA.x) * wA; acc[1] += bf_hi(hA.x) * wA;
            acc[2] += bf_lo(hA.y) * wA; acc[3] += bf_hi(hA.y) * wA;
            acc[4] += bf_lo(hA.z) * wA; acc[5] += bf_hi(hA.z) * wA;
            acc[6] += bf_lo(hA.w) * wA; acc[7] += bf_hi(hA.w) * wA;
            acc[0] += bf_lo(hB.x) * wB; acc[1] += bf_hi(hB.x) * wB;
            acc[2] += bf_lo(hB.y) * wB; acc[3] += bf_hi(hB.y) * wB;
            acc[4] += bf_lo(hB.z) * wB; acc[5] += bf_hi(hB.z) * wB;
            acc[6] += bf_lo(hB.w) * wB; acc[7] += bf_hi(hB.w) * wB;
        }
        if (g < groups) {
            int   sA = __shfl(sid, g * 8 + slot);
            float wA = __shfl(wgt, g * 8 + slot);
            uint4 hA = *(const uint4*)&h[(size_t)sA * F_HID + (c << 3)];
            acc[0] += bf_lo(hA.x) * wA; acc[1] += bf_hi(hA.x) * wA;
            acc[2] += bf_lo(hA.y) * wA; acc[3] += bf_hi(hA.y) * wA;
            acc[4] += bf_lo(hA.z) * wA; acc[5] += bf_hi(hA.z) * wA;
            acc[6] += bf_lo(hA.w) * wA; acc[7] += bf_hi(hA.w) * wA;
        }
    }
    #pragma unroll
    for (int m = 8; m < 64; m <<= 1) {
        #pragma unroll
        for (int k = 0; k < 8; ++k) acc[k] += __shfl_xor(acc[k], m);
    }
    if (slot == 0) {
        float di = dinv[node];
        uint4 hs = *(const uint4*)&h[(size_t)node * F_HID + (c << 3)];
        float self[8] = { bf_lo(hs.x), bf_hi(hs.x), bf_lo(hs.y), bf_hi(hs.y),
                          bf_lo(hs.z), bf_hi(hs.z), bf_lo(hs.w), bf_hi(hs.w) };
        float4 b0 = *(const float4*)&b[c << 3];
        float4 b1v = *(const float4*)&b[(c << 3) + 4];
        float bb[8] = { b0.x, b0.y, b0.z, b0.w, b1v.x, b1v.y, b1v.z, b1v.w };
        ushort o[8];
        #pragma unroll
        for (int k = 0; k < 8; ++k) {
            float v = fmaxf(acc[k] * di + self[k] * di * di + bb[k], 0.f);
            o[k] = f2bf(v);
        }
        uint4 pk;
        pk.x = (uint)o[0] | ((uint)o[1] << 16);
        pk.y = (uint)o[2] | ((uint)o[3] << 16);
        pk.z = (uint)o[4] | ((uint)o[5] << 16);
        pk.w = (uint)o[6] | ((uint)o[7] << 16);
        *(uint4*)&out[(size_t)node * F_HID + (c << 3)] = pk;
    }
}

// ---------------- GEMM2: h2b[N,40](bf16) = out1b[N,64](bf16) @ W2[64,40] ----------
__global__ void gemm2_kernel(const ushort* __restrict__ a, const float* __restrict__ W,
                             ushort* __restrict__ h, int n) {
    __shared__ float Wl[F_HID * F_OUT];
    int tid = threadIdx.x;
    for (int i = tid; i < F_HID * F_OUT; i += 256) Wl[i] = W[i];
    __syncthreads();
    long long idx = (long long)blockIdx.x * 256 + tid;
    if (idx >= (long long)n * F_OUT) return;
    int node = (int)(idx / F_OUT);
    int col  = (int)(idx - (long long)node * F_OUT);
    const uint* arow = (const uint*)(a + (size_t)node * F_HID);
    float acc = 0.0f;
    #pragma unroll 8
    for (int k = 0; k < F_HID / 2; ++k) {
        uint u = arow[k];
        acc += bf_lo(u) * Wl[(2 * k) * F_OUT + col] + bf_hi(u) * Wl[(2 * k + 1) * F_OUT + col];
    }
    h[idx] = f2bf(acc);
}

// ---------------- layer-2 gather + combine + log_softmax (pipelined) --------------
__global__ void agg2_kernel(const int* __restrict__ rowstart, const int* __restrict__ csr,
                            const float* __restrict__ dinv, const ushort* __restrict__ h,
                            const float* __restrict__ b, float* __restrict__ out, int n) {
    int node = blockIdx.x * 4 + (threadIdx.x >> 6);
    int lane = threadIdx.x & 63;
    if (node >= n) return;
    int slot = lane / 10;            // 0..6 (lanes 60..63 idle slot)
    int c    = lane - slot * 10;     // chunk -> features c*4..c*4+3
    int beg = rowstart[node], end = rowstart[node + 1];
    float acc[4] = {0.f, 0.f, 0.f, 0.f};
    for (int base = beg; base < end; base += 60) {
        int idx = base + lane;
        int   sid = 0; float wgt = 0.f;
        if (lane < 60 && idx < end) { sid = csr[idx]; wgt = dinv[sid]; }
        int cnt    = min(60, end - base);
        int groups = (cnt + 5) / 6;
        int slbase = (slot < 6) ? slot : 60;   // lane 60 has wgt=0, sid=0
        int g = 0;
        for (; g + 2 <= groups; g += 2) {
            int   slA = (slot < 6) ? (g * 6 + slot) : 60;
            int   slB = (slot < 6) ? (g * 6 + 6 + slot) : 60;
            int   sA = __shfl(sid, slA);
            float wA = __shfl(wgt, slA);
            int   sB = __shfl(sid, slB);
            float wB = __shfl(wgt, slB);
            uint2 hA = *(const uint2*)&h[(size_t)sA * F_OUT + (c << 2)];
            uint2 hB = *(const uint2*)&h[(size_t)sB * F_OUT + (c << 2)];
            acc[0] += bf_lo(hA.x) * wA; acc[1] += bf_hi(hA.x) * wA;
            acc[2] += bf_lo(hA.y) * wA; acc[3] += bf_hi(hA.y) * wA;
            acc[0] += bf_lo(hB.x) * wB; acc[1] += bf_hi(hB.x) * wB;
            acc[2] += bf_lo(hB.y) * wB; acc[3] += bf_hi(hB.y) * wB;
        }
        if (g < groups) {
            int   slA = (slot < 6) ? (g * 6 + slot) : 60;
            int   sA = __shfl(sid, slA);
            float wA = __shfl(wgt, slA);
            uint2 hA = *(const uint2*)&h[(size_t)sA * F_OUT + (c << 2)];
            acc[0] += bf_lo(hA.x) * wA; acc[1] += bf_hi(hA.x) * wA;
            acc[2] += bf_lo(hA.y) * wA; acc[3] += bf_hi(hA.y) * wA;
        }
        (void)slbase;
    }
    // slot reduction: 6 -> 3 -> 1 (3 serial shfl steps)
    float r[4];
    #pragma unroll
    for (int k = 0; k < 4; ++k) {
        float t3 = __shfl(acc[k], lane + 30);          // slots 3..5 -> 0..2
        float s0 = acc[k] + t3;                        // valid for lanes < 30
        float t1 = __shfl(s0, lane + 10);              // slot 1 -> 0
        float t2 = __shfl(s0, lane + 20);              // slot 2 -> 0
        r[k] = s0 + t1 + t2;                           // valid for lanes < 10
    }
    float val[4] = {0.f, 0.f, 0.f, 0.f};
    float m = -INFINITY;
    if (lane < 10) {
        float di = dinv[node];
        uint2 hs = *(const uint2*)&h[(size_t)node * F_OUT + (c << 2)];
        float self[4] = { bf_lo(hs.x), bf_hi(hs.x), bf_lo(hs.y), bf_hi(hs.y) };
        float4 bb = *(const float4*)&b[c << 2];
        float bbv[4] = { bb.x, bb.y, bb.z, bb.w };
        #pragma unroll
        for (int k = 0; k < 4; ++k) {
            val[k] = r[k] * di + self[k] * di * di + bbv[k];
            m = fmaxf(m, val[k]);
        }
    }
    #pragma unroll
    for (int off = 1; off < 16; off <<= 1) m = fmaxf(m, __shfl_xor(m, off));
    float p = 0.f;
    if (lane < 10)
        p = __expf(val[0] - m) + __expf(val[1] - m) + __expf(val[2] - m) + __expf(val[3] - m);
    #pragma unroll
    for (int off = 1; off < 16; off <<= 1) p += __shfl_xor(p, off);
    float lse = m + __logf(p);
    if (lane < 10) {
        float4 o;
        o.x = val[0] - lse; o.y = val[1] - lse; o.z = val[2] - lse; o.w = val[3] - lse;
        *(float4*)&out[(size_t)node * F_OUT + (c << 2)] = o;
    }
}

extern "C" void kernel_launch(void* const* d_in, const int* in_sizes, int n_in,
                              void* d_out, int out_size, void* d_ws, size_t ws_size,
                              hipStream_t stream) {
    const float* x  = (const float*)d_in[0];
    const int*   ei = (const int*)d_in[1];
    const float* W1 = (const float*)d_in[2];
    const float* b1 = (const float*)d_in[3];
    const float* W2 = (const float*)d_in[4];
    const float* b2 = (const float*)d_in[5];
    const int* src = ei;
    const int* dst = ei + N_EDGES;

    // workspace layout (all chunks 16B-aligned)
    char* p = (char*)d_ws;
    int*    bcount   = (int*)p;     p += (size_t)(NBINS + 4) * 4;
    int*    bstart   = (int*)p;     p += (size_t)(NBINS + 4) * 4;
    int*    bcursor  = (int*)p;     p += (size_t)(NBINS + 4) * 4;
    int*    bins     = (int*)p;     p += (size_t)N_EDGES * 4;
    int*    csr_src  = (int*)p;     p += (size_t)N_EDGES * 4;
    int*    rowstart = (int*)p;     p += (size_t)(N_NODES + 4) * 4;
    float*  dinv     = (float*)p;   p += (size_t)N_NODES * 4;
    uint*   Wtb      = (uint*)p;    p += (size_t)4096 * 4;       // W1^T bf16 [64][128]
    ushort* h1b      = (ushort*)p;  p += (size_t)N_NODES * F_HID * 2;
    ushort* out1b    = (ushort*)p;  p += (size_t)N_NODES * F_HID * 2;
    ushort* h2b      = (ushort*)p;  p += (size_t)N_NODES * F_OUT * 2;
    float*  out      = (float*)d_out;

    hipMemsetAsync(bcount, 0, (size_t)NBINS * 4, stream);

    bincount_kernel<<<FILL_BLOCKS, 256, 0, stream>>>(dst, bcount, N_EDGES);
    binscan_kernel <<<1, 256, 0, stream>>>(bcount, bstart, bcursor, rowstart);
    binfill_kernel <<<FILL_BLOCKS, 256, 0, stream>>>(src, dst, bcursor, bins, N_EDGES);
    binsort_kernel <<<NBINS, 512, 0, stream>>>(bstart, bins, csr_src, rowstart, dinv);
    wtrans_kernel<<<1, 256, 0, stream>>>(W1, Wtb);
    gemm1_kernel<<<(N_NODES + 63) / 64, 256, 0, stream>>>(x, Wtb, h1b, N_NODES);
    agg1_kernel <<<(N_NODES + 3) / 4, 256, 0, stream>>>(rowstart, csr_src, dinv, h1b, b1,
                                                        out1b, N_NODES);
    gemm2_kernel<<<((N_NODES * F_OUT) + 255) / 256, 256, 0, stream>>>(out1b, W2, h2b, N_NODES);
    agg2_kernel <<<(N_NODES + 3) / 4, 256, 0, stream>>>(rowstart, csr_src, dinv, h2b, b2,
                                                        out, N_NODES);
}